// Round 11
// baseline (801.172 us; speedup 1.0000x reference)
//
#include <hip/hip_runtime.h>
#include <hip/hip_bf16.h>

#define N_NODES 50176
#define PER 392
#define E_BI (N_NODES * 4)      // 200704
#define E_KNN (N_NODES * 16)    // 802816
#define E_TOT (E_BI + E_KNN)    // 1003520
#define KN_BI (N_NODES * 5)     // 250880
#define KN_TOT (N_NODES * 14)   // 702464
#define AH_S 416                // ah row stride (shorts): [a(128)|h(128)|cnt(32)|feat(128)]
#define AH_U 208                // ... in uints

typedef __attribute__((ext_vector_type(8))) short short8;
typedef __attribute__((ext_vector_type(4))) float float4v;
typedef unsigned int uint;
typedef unsigned short ushort;

__device__ __forceinline__ float sigmoidf_(float x) { return 1.f / (1.f + __expf(-x)); }
__device__ __forceinline__ ushort f2bu(float x) {
    __hip_bfloat16 t = __float2bfloat16(x);
    return *reinterpret_cast<ushort*>(&t);
}
__device__ __forceinline__ float blo(uint u) { return __uint_as_float(u << 16); }
__device__ __forceinline__ float bhi(uint u) { return __uint_as_float(u & 0xFFFF0000u); }

// ================= fused aggregate + per-etype transform (v6: edge-parity split) ======
// Block = 32 node rows, 512 threads: 16 threads/row = 2 parity groups x 8 (16 ch each,
// 2x16B loads/edge — v4's proven load shape). Parity groups take alternate edges;
// combine via shfl_xor(8). 8 waves x acc[2] MFMA (16 rows x 32 cols each).
template<int NET>
__global__ __launch_bounds__(512) void msg_kernel(
    const uint* __restrict__ hb,           // [N][64] uints (h bf16 packed)
    const int* __restrict__ indptr,        // [N*NET+1] slice (absolute into elist)
    const int* __restrict__ elist,
    const ushort* __restrict__ Bfrag,      // fragment-ordered weights
    ushort* __restrict__ aout)             // target ah buffer; write cols 0..127
{
    __shared__ ushort As[4][32][40];       // 10.25 KB, chunk-major, 80B rows
    const int tid = threadIdx.x;
    const int bm = blockIdx.x * 32;
    const int wave = tid >> 6, lane = tid & 63;
    const int quad = lane >> 4, lrow = lane & 15;
    const int wr = wave & 1, wcol = wave >> 1;   // wr 0..1 (row half), wcol 0..3 (col 32-group)
    const int r = tid >> 4;                // node row 0..31
    const int par = (tid >> 3) & 1;        // edge parity
    const int oct = tid & 7;               // 16-ch group
    const int v = bm + r;

    uint* AsU = (uint*)As;                 // [ch][r][20] uints

    float4v acc[2] = {};

    for (int et = 0; et < NET; et++) {
        const int beg = indptr[v * NET + et], end = indptr[v * NET + et + 1];
        float av[16];
#pragma unroll
        for (int i = 0; i < 16; i++) av[i] = 0.f;

        for (int j = beg + par; j < end; j += 2) {
            int src = elist[j];
            const uint4* hp = (const uint4*)(hb + (size_t)src * 64 + oct * 8);
            uint4 u0 = hp[0];
            uint4 u1 = hp[1];
            av[0] += blo(u0.x); av[1] += bhi(u0.x);
            av[2] += blo(u0.y); av[3] += bhi(u0.y);
            av[4] += blo(u0.z); av[5] += bhi(u0.z);
            av[6] += blo(u0.w); av[7] += bhi(u0.w);
            av[8]  += blo(u1.x); av[9]  += bhi(u1.x);
            av[10] += blo(u1.y); av[11] += bhi(u1.y);
            av[12] += blo(u1.z); av[13] += bhi(u1.z);
            av[14] += blo(u1.w); av[15] += bhi(u1.w);
        }
        // combine parity halves (partner lane = lane ^ 8, same wave)
#pragma unroll
        for (int i = 0; i < 16; i++) av[i] += __shfl_xor(av[i], 8);

        __syncthreads();                   // previous etype's As reads complete
        if (par == 0) {
            int base = ((oct >> 1) * 32 + r) * 20 + (oct & 1) * 8;
#pragma unroll
            for (int u = 0; u < 8; u++)
                AsU[base + u] = (uint)f2bu(av[2 * u]) | ((uint)f2bu(av[2 * u + 1]) << 16);
        }
        __syncthreads();

#pragma unroll
        for (int ch = 0; ch < 4; ch++) {
            short8 af = *(const short8*)&As[ch][wr * 16 + lrow][quad * 8];
            const ushort* bp = Bfrag +
                ((size_t)((((et * 4 + ch) * 2 + (wcol >> 1)) * 4) + (wcol & 1) * 2) << 9)
                + lane * 8;
#pragma unroll
            for (int j = 0; j < 2; j++) {
                short8 bfr = *(const short8*)(bp + j * 512);
                acc[j] = __builtin_amdgcn_mfma_f32_16x16x32_bf16(af, bfr, acc[j], 0, 0, 0);
            }
        }
    }

#pragma unroll
    for (int j = 0; j < 2; j++) {
        int col = wcol * 32 + j * 16 + lrow;
#pragma unroll
        for (int rr = 0; rr < 4; rr++) {
            size_t row = (size_t)(bm + wr * 16 + quad * 4 + rr);
            aout[row * AH_S + col] = f2bu(acc[j][rr]);
        }
    }
}

// ================= GRU GEMM with fused gate epilogue (ping-pong, race-free) ============
__global__ __launch_bounds__(256) void gru_gemm_kernel(
    const ushort* __restrict__ A,          // ahIn base, lda AH_S
    const ushort* __restrict__ Bt,         // gruB [512][288] permuted
    const float* __restrict__ bias,        // [512] permuted
    float* __restrict__ h,
    ushort* __restrict__ ahOut, ushort* __restrict__ hbS)
{
    __shared__ ushort As[128 * 32];
    __shared__ ushort Bs[128 * 32];
    const int tid = threadIdx.x;
    const int bm = blockIdx.x * 128;
    const int bn = blockIdx.y * 128;
    const int wave = tid >> 6, lane = tid & 63;
    const int quad = lane >> 4, lrow = lane & 15;
    const int wr = wave & 1, wc = wave >> 1;

    float4v acc[4][4] = {};

    for (int k0 = 0; k0 < 288; k0 += 32) {
        __syncthreads();
#pragma unroll
        for (int p = 0; p < 2; p++) {
            int lin = p * 256 + tid;
            int r = lin >> 2;
            int kc = (lin & 3) * 8;
            *(short8*)&As[r * 32 + kc] = *(const short8*)(A + (size_t)(bm + r) * AH_S + k0 + kc);
            *(short8*)&Bs[r * 32 + kc] = *(const short8*)(Bt + (size_t)(bn + r) * 288 + k0 + kc);
        }
        __syncthreads();
        short8 af[4], bfr[4];
#pragma unroll
        for (int i = 0; i < 4; i++)
            af[i] = *(const short8*)&As[(wr * 64 + i * 16 + lrow) * 32 + quad * 8];
#pragma unroll
        for (int j = 0; j < 4; j++)
            bfr[j] = *(const short8*)&Bs[(wc * 64 + j * 16 + lrow) * 32 + quad * 8];
#pragma unroll
        for (int i = 0; i < 4; i++)
#pragma unroll
            for (int j = 0; j < 4; j++)
                acc[i][j] = __builtin_amdgcn_mfma_f32_16x16x32_bf16(af[i], bfr[j], acc[i][j], 0, 0, 0);
    }

    const int ch = (bn >> 7) * 32 + wc * 16 + lrow;
    const float b0 = bias[bn + wc * 64 + lrow];
    const float b1 = bias[bn + wc * 64 + 16 + lrow];
    const float b2 = bias[bn + wc * 64 + 32 + lrow];
    const float b3 = bias[bn + wc * 64 + 48 + lrow];
#pragma unroll
    for (int i = 0; i < 4; i++) {
#pragma unroll
        for (int r = 0; r < 4; r++) {
            size_t row = (size_t)(bm + wr * 64 + i * 16 + quad * 4 + r);
            float rr = sigmoidf_(acc[i][0][r] + b0);
            float zz = sigmoidf_(acc[i][1][r] + b1);
            float nn = tanhf(acc[i][2][r] + b2 + rr * (acc[i][3][r] + b3));
            float hold = h[row * 128 + ch];
            float hnew = (1.f - zz) * nn + zz * hold;
            h[row * 128 + ch] = hnew;
            ushort hu = f2bu(hnew);
            ahOut[row * AH_S + 128 + ch] = hu;
            hbS[row * 128 + ch] = hu;
        }
    }
}

// ================= readout GEMM with fused sigmoid-mul epilogue =================
__global__ __launch_bounds__(256) void ro_gemm_kernel(
    const ushort* __restrict__ A,
    const ushort* __restrict__ Bt,         // [256][288]
    const float* __restrict__ bias,        // [256] permuted
    float* __restrict__ rout, ushort* __restrict__ rb)
{
    __shared__ ushort As[128 * 32];
    __shared__ ushort Bs[128 * 32];
    const int tid = threadIdx.x;
    const int bm = blockIdx.x * 128;
    const int bn = blockIdx.y * 128;
    const int wave = tid >> 6, lane = tid & 63;
    const int quad = lane >> 4, lrow = lane & 15;
    const int wr = wave & 1, wc = wave >> 1;

    float4v acc[4][4] = {};

    for (int k0 = 0; k0 < 288; k0 += 32) {
        __syncthreads();
#pragma unroll
        for (int p = 0; p < 2; p++) {
            int lin = p * 256 + tid;
            int r = lin >> 2;
            int kc = (lin & 3) * 8;
            *(short8*)&As[r * 32 + kc] = *(const short8*)(A + (size_t)(bm + r) * AH_S + k0 + kc);
            *(short8*)&Bs[r * 32 + kc] = *(const short8*)(Bt + (size_t)(bn + r) * 288 + k0 + kc);
        }
        __syncthreads();
        short8 af[4], bfr[4];
#pragma unroll
        for (int i = 0; i < 4; i++)
            af[i] = *(const short8*)&As[(wr * 64 + i * 16 + lrow) * 32 + quad * 8];
#pragma unroll
        for (int j = 0; j < 4; j++)
            bfr[j] = *(const short8*)&Bs[(wc * 64 + j * 16 + lrow) * 32 + quad * 8];
#pragma unroll
        for (int i = 0; i < 4; i++)
#pragma unroll
            for (int j = 0; j < 4; j++)
                acc[i][j] = __builtin_amdgcn_mfma_f32_16x16x32_bf16(af[i], bfr[j], acc[i][j], 0, 0, 0);
    }

    const int c0 = (bn >> 7) * 64 + wc * 32 + lrow;
    const int c1 = c0 + 16;
    const float bu0 = bias[bn + wc * 64 + lrow];
    const float bv0 = bias[bn + wc * 64 + 16 + lrow];
    const float bu1 = bias[bn + wc * 64 + 32 + lrow];
    const float bv1 = bias[bn + wc * 64 + 48 + lrow];
#pragma unroll
    for (int i = 0; i < 4; i++) {
#pragma unroll
        for (int r = 0; r < 4; r++) {
            size_t row = (size_t)(bm + wr * 64 + i * 16 + quad * 4 + r);
            float o0 = sigmoidf_(acc[i][0][r] + bu0) * (acc[i][1][r] + bv0);
            float o1 = sigmoidf_(acc[i][2][r] + bu1) * (acc[i][3][r] + bv1);
            if (rout) { rout[row * 128 + c0] = o0; rout[row * 128 + c1] = o1; }
            if (rb)   { rb[row * 128 + c0] = f2bu(o0); rb[row * 128 + c1] = f2bu(o1); }
        }
    }
}

// ================= small fp32 GEMM (stage-3 MLP only) =================
__global__ __launch_bounds__(256) void gemm_kernel(
    const float* __restrict__ A, int lda,
    const float* __restrict__ B, int ldb,
    const float* __restrict__ bias,
    float* __restrict__ C, int ldc,
    int K, int act)
{
    __shared__ float As[32][68];
    __shared__ float Bs[32][68];
    const int tid = threadIdx.x;
    const int bm = blockIdx.x * 64;
    const int bn = blockIdx.y * 64;
    const int tm = (tid & 15) * 4;
    const int tn = (tid >> 4) * 4;
    float acc[4][4] = {};

    for (int k0 = 0; k0 < K; k0 += 32) {
#pragma unroll
        for (int p = 0; p < 2; p++) {
            int lin = p * 256 + tid;
            int ar = lin >> 3;
            int ac = (lin & 7) << 2;
            float4 av = *(const float4*)(A + (size_t)(bm + ar) * lda + (k0 + ac));
            As[ac + 0][ar] = av.x;
            As[ac + 1][ar] = av.y;
            As[ac + 2][ar] = av.z;
            As[ac + 3][ar] = av.w;
            int br = lin >> 4;
            int bc = (lin & 15) << 2;
            *(float4*)&Bs[br][bc] = *(const float4*)(B + (size_t)(k0 + br) * ldb + (bn + bc));
        }
        __syncthreads();
#pragma unroll
        for (int k = 0; k < 32; k++) {
            float4 a4 = *(const float4*)&As[k][tm];
            float4 b4 = *(const float4*)&Bs[k][tn];
            float av[4] = {a4.x, a4.y, a4.z, a4.w};
            float bv[4] = {b4.x, b4.y, b4.z, b4.w};
#pragma unroll
            for (int i = 0; i < 4; i++)
#pragma unroll
                for (int j = 0; j < 4; j++)
                    acc[i][j] += av[i] * bv[j];
        }
        __syncthreads();
    }
#pragma unroll
    for (int i = 0; i < 4; i++) {
        size_t row = (size_t)(bm + tm + i);
#pragma unroll
        for (int j = 0; j < 4; j++) {
            int col = bn + tn + j;
            float val = acc[i][j] + (bias ? bias[col] : 0.f);
            if (act == 1) val = fmaxf(val, 0.f);
            C[row * ldc + col] = val;
        }
    }
}

// ================= weight prep =================
// Bfrag[(((et*4+ch)*2+wc)*4 + j)][lane][m] = W[et][k][c], k=ch*32+quad*8+m, c=wc*64+j*16+lrow
__global__ void prep_bfrag_kernel(const float* __restrict__ W, __hip_bfloat16* __restrict__ Bf,
                                  int net)
{
    int idx = blockIdx.x * blockDim.x + threadIdx.x;   // net*16384
    int m = idx & 7;
    int lane = (idx >> 3) & 63;
    int f = idx >> 9;
    int j = f & 3; f >>= 2;
    int wc = f & 1; f >>= 1;
    int ch = f & 3;
    int et = f >> 2;
    int quad = lane >> 4, lrow = lane & 15;
    int k = ch * 32 + quad * 8 + m;
    int c = wc * 64 + j * 16 + lrow;
    Bf[idx] = __float2bfloat16(W[et * 16384 + k * 128 + c]);
}

// GRU fused weights, output-col permuted: p -> gate g=(p>>4)&3, ch c=(p>>7)*32+((p>>6)&1)*16+(p&15)
__global__ void prep_gru_kernel(const float* __restrict__ wih, const float* __restrict__ whh,
                                const float* __restrict__ bih, const float* __restrict__ bhh,
                                const float* __restrict__ b, int net,
                                __hip_bfloat16* __restrict__ Bt, float* __restrict__ bias)
{
    int idx = blockIdx.x * blockDim.x + threadIdx.x;   // 512*288
    int p = idx / 288;
    int k = idx - p * 288;
    int g = (p >> 4) & 3;
    int c = (p >> 7) * 32 + ((p >> 6) & 1) * 16 + (p & 15);
    float val = 0.f;
    if (k < 128) {                                     // from a
        if (g == 0)      val = wih[k * 384 + c];
        else if (g == 1) val = wih[k * 384 + 128 + c];
        else if (g == 2) val = wih[k * 384 + 256 + c];
    } else if (k < 256) {                              // from h
        int kk = k - 128;
        if (g == 0)      val = whh[kk * 384 + c];
        else if (g == 1) val = whh[kk * 384 + 128 + c];
        else if (g == 3) val = whh[kk * 384 + 256 + c];
    } else {                                           // cnt cols: b @ wih
        int j = k - 256;
        if (j < net && g < 3) {
            int col = g * 128 + c;
            float s = 0.f;
            for (int kk = 0; kk < 128; kk++) s += b[j * 128 + kk] * wih[kk * 384 + col];
            val = s;
        }
    }
    Bt[idx] = __float2bfloat16(val);
    if (k == 0) {
        float bv;
        if (g == 0)      bv = bih[c] + bhh[c];
        else if (g == 1) bv = bih[128 + c] + bhh[128 + c];
        else if (g == 2) bv = bih[256 + c];
        else             bv = bhh[256 + c];
        bias[p] = bv;
    }
}

// Readout weights [256][288]: p -> side s=j&1 (0=u/iw,1=v/jw), ch = blk*64+wc*32+(j>>1)*16+t
__global__ void prep_ro_kernel(const float* __restrict__ iw, const float* __restrict__ jw,
                               const float* __restrict__ ib, const float* __restrict__ jb,
                               int Fin, __hip_bfloat16* __restrict__ Bt,
                               float* __restrict__ bias)
{
    int idx = blockIdx.x * blockDim.x + threadIdx.x;   // 256*288
    int p = idx / 288;
    int k = idx - p * 288;
    int j = (p >> 4) & 3;
    int s = j & 1;
    int c = ((p >> 7) & 1) * 64 + ((p >> 6) & 1) * 32 + (j >> 1) * 16 + (p & 15);
    float val = 0.f;
    if (k < 128) {
        val = s ? jw[k * 128 + c] : iw[k * 128 + c];
    } else if (k >= 160) {
        int kf = k - 160;
        if (kf < Fin && s == 0) val = iw[(128 + kf) * 128 + c];
    }
    Bt[idx] = __float2bfloat16(val);
    if (k == 0) bias[p] = s ? jb[c] : ib[c];
}

// ================= merged CSR build =================
__global__ void hist2_kernel(const int* __restrict__ bd, const int* __restrict__ be,
                             const int* __restrict__ kd, const int* __restrict__ ke,
                             int* __restrict__ counts)
{
    int e = blockIdx.x * blockDim.x + threadIdx.x;
    if (e >= E_TOT) return;
    if (e < E_BI) atomicAdd(&counts[bd[e] * 5 + be[e]], 1);
    else { int i = e - E_BI; atomicAdd(&counts[KN_BI + kd[i] * 9 + ke[i]], 1); }
}

__global__ void scan1_kernel(const int* __restrict__ counts, int* __restrict__ local_ex,
                             int* __restrict__ partial)
{
    __shared__ int s[256];
    int t = threadIdx.x;
    int i = blockIdx.x * 256 + t;
    int v = counts[i];
    s[t] = v;
    __syncthreads();
    for (int off = 1; off < 256; off <<= 1) {
        int x = 0;
        if (t >= off) x = s[t - off];
        __syncthreads();
        if (t >= off) s[t] += x;
        __syncthreads();
    }
    local_ex[i] = s[t] - v;
    if (t == 255) partial[blockIdx.x] = s[255];
}

__global__ void scan2b_kernel(int* __restrict__ partial, int nb, int* __restrict__ last, int E)
{
    __shared__ int s[256];
    int t = threadIdx.x;
    int loc[11];
    int sum = 0;
#pragma unroll
    for (int q = 0; q < 11; q++) {
        int idx = t * 11 + q;
        int v = (idx < nb) ? partial[idx] : 0;
        loc[q] = sum; sum += v;
    }
    s[t] = sum;
    __syncthreads();
    for (int off = 1; off < 256; off <<= 1) {
        int x = 0;
        if (t >= off) x = s[t - off];
        __syncthreads();
        if (t >= off) s[t] += x;
        __syncthreads();
    }
    int excl = s[t] - sum;
#pragma unroll
    for (int q = 0; q < 11; q++) {
        int idx = t * 11 + q;
        if (idx < nb) partial[idx] = excl + loc[q];
    }
    if (t == 0) *last = E;
}

__global__ void scan3c_kernel(int* __restrict__ indptr, const int* __restrict__ partial,
                              int* __restrict__ cursor)
{
    int i = blockIdx.x * 256 + threadIdx.x;
    int v = indptr[i] + partial[blockIdx.x];
    indptr[i] = v;
    cursor[i] = v;
}

__global__ void fill2_kernel(const int* __restrict__ bs, const int* __restrict__ bd,
                             const int* __restrict__ be,
                             const int* __restrict__ ks, const int* __restrict__ kd,
                             const int* __restrict__ ke,
                             int* __restrict__ cursor, int* __restrict__ elist)
{
    int e = blockIdx.x * blockDim.x + threadIdx.x;
    if (e >= E_TOT) return;
    if (e < E_BI) {
        int pos = atomicAdd(&cursor[bd[e] * 5 + be[e]], 1);
        elist[pos] = bs[e];
    } else {
        int i = e - E_BI;
        int pos = atomicAdd(&cursor[KN_BI + kd[i] * 9 + ke[i]], 1);
        elist[pos] = ks[i];
    }
}

// ================= elementwise: pad + cnt fused =================
// feat -> h fp32, ahA h-cols, feat cols (both buffers), hb; cnt cols (both buffers)
__global__ void pad_cnt_kernel(const float* __restrict__ fsrc, const ushort* __restrict__ bsrc,
                               const int* __restrict__ indptr, int net,
                               float* __restrict__ h, uint* __restrict__ ahA,
                               uint* __restrict__ ahB, uint* __restrict__ hb, int Fin)
{
    int idx = blockIdx.x * blockDim.x + threadIdx.x;   // N*32
    int v = idx >> 5;
    int j = idx & 31;
    int c = j * 4;
    float4 val = make_float4(0.f, 0.f, 0.f, 0.f);
    if (bsrc) {
        uint2 u = *(const uint2*)(bsrc + (size_t)v * Fin + c);
        val.x = blo(u.x); val.y = bhi(u.x);
        val.z = blo(u.y); val.w = bhi(u.y);
    } else if (c < Fin) {
        val = *(const float4*)(fsrc + (size_t)v * Fin + c);
    }
    *(float4*)(h + (size_t)v * 128 + c) = val;
    uint2 pk;
    pk.x = (uint)f2bu(val.x) | ((uint)f2bu(val.y) << 16);
    pk.y = (uint)f2bu(val.z) | ((uint)f2bu(val.w) << 16);
    *(uint2*)(ahA + (size_t)v * AH_U + 64 + c / 2) = pk;    // h cols (step-0 input)
    *(uint2*)(ahA + (size_t)v * AH_U + 144 + c / 2) = pk;   // feat cols
    *(uint2*)(ahB + (size_t)v * AH_U + 144 + c / 2) = pk;
    *(uint2*)(hb + (size_t)v * 64 + c / 2) = pk;
    // cnt col j
    float cv = 0.f;
    if (j < net) cv = (float)(indptr[v * net + j + 1] - indptr[v * net + j]);
    ushort u = f2bu(cv);
    ((ushort*)ahA)[(size_t)v * AH_S + 256 + j] = u;
    ((ushort*)ahB)[(size_t)v * AH_S + 256 + j] = u;
}

__global__ void pool_kernel(const float* __restrict__ r2, float* __restrict__ pooled)
{
    int s = blockIdx.x;
    int c = threadIdx.x;
    const float* base = r2 + (size_t)(2 * s) * PER * 128;
    float acc = 0.f;
    for (int i = 0; i < PER; i++) acc += base[(size_t)i * 128 + c];
    pooled[s * 128 + c] = acc;
}

__global__ void out_kernel(const float* __restrict__ x2, const float* __restrict__ wo,
                           const float* __restrict__ bo, float* __restrict__ out)
{
    int row = blockIdx.x;
    int t = threadIdx.x;
    float s = x2[row * 128 + t] * wo[t] + x2[row * 128 + 64 + t] * wo[64 + t];
#pragma unroll
    for (int off = 32; off; off >>= 1) s += __shfl_down(s, off);
    if (t == 0) out[row] = s + bo[0];
}

struct GGParams {
    const float *W, *b, *wih, *whh, *bih, *bhh, *iw, *ib, *jw, *jb;
};

struct WsPtrs {
    float* h;
    __hip_bfloat16 *ah0, *ah1;   // [N,416] bf16 ping-pong
    float* G;                    // 2*n128: rout2 | hb
    uint* hb;
    __hip_bfloat16* r1b;
    __hip_bfloat16 *bfragB, *gruB, *roB;
    float *gruBias, *roBias;
    int *indptr, *cursor, *partial, *elist;
    float *pooled, *x1, *x2;
};

template<int NET>
static void run_stage(hipStream_t st, const float* featF, const __hip_bfloat16* featB, int Fin,
                      const GGParams& p, const WsPtrs& w, const int* indptr_slice,
                      float* rout, __hip_bfloat16* rout_b)
{
    const int N = N_NODES;
    ushort* ahA = (ushort*)w.ah0;
    ushort* ahB = (ushort*)w.ah1;
    ushort* hbS = (ushort*)w.hb;

    prep_bfrag_kernel<<<(NET * 16384) / 256, 256, 0, st>>>(p.W, w.bfragB, NET);
    prep_gru_kernel<<<(512 * 288) / 256, 256, 0, st>>>(p.wih, p.whh, p.bih, p.bhh, p.b, NET,
                                                       w.gruB, w.gruBias);
    prep_ro_kernel<<<(256 * 288) / 256, 256, 0, st>>>(p.iw, p.jw, p.ib, p.jb, Fin,
                                                      w.roB, w.roBias);

    pad_cnt_kernel<<<(N * 32) / 256, 256, 0, st>>>(featF, (const ushort*)featB,
                                                   indptr_slice, NET, w.h,
                                                   (uint*)ahA, (uint*)ahB, w.hb, Fin);

    ushort* ahIn = ahA;
    ushort* ahOut = ahB;
    for (int step = 0; step < 2; step++) {
        msg_kernel<NET><<<N / 32, 512, 0, st>>>(w.hb, indptr_slice, w.elist,
                                                (ushort*)w.bfragB, ahIn);
        dim3 g(N / 128, 4);
        gru_gemm_kernel<<<g, 256, 0, st>>>(ahIn, (ushort*)w.gruB, w.gruBias, w.h, ahOut, hbS);
        ushort* t = ahIn; ahIn = ahOut; ahOut = t;
    }
    // after 2 steps, latest h lives in ahIn together with cnt|feat
    dim3 gr(N / 128, 2);
    ro_gemm_kernel<<<gr, 256, 0, st>>>(ahIn + 128, (ushort*)w.roB, w.roBias,
                                       rout, (ushort*)rout_b);
}

extern "C" void kernel_launch(void* const* d_in, const int* in_sizes, int n_in,
                              void* d_out, int out_size, void* d_ws, size_t ws_size,
                              hipStream_t stream)
{
    const float* feat    = (const float*)d_in[0];
    const int*   bi_src  = (const int*)d_in[1];
    const int*   bi_dst  = (const int*)d_in[2];
    const int*   bi_et   = (const int*)d_in[3];
    const int*   knn_src = (const int*)d_in[4];
    const int*   knn_dst = (const int*)d_in[5];
    const int*   knn_et  = (const int*)d_in[6];

    GGParams s1 { (const float*)d_in[8],  (const float*)d_in[9],  (const float*)d_in[10],
                  (const float*)d_in[11], (const float*)d_in[12], (const float*)d_in[13],
                  (const float*)d_in[14], (const float*)d_in[15], (const float*)d_in[16],
                  (const float*)d_in[17] };
    GGParams s2 { (const float*)d_in[18], (const float*)d_in[19], (const float*)d_in[20],
                  (const float*)d_in[21], (const float*)d_in[22], (const float*)d_in[23],
                  (const float*)d_in[24], (const float*)d_in[25], (const float*)d_in[26],
                  (const float*)d_in[27] };
    const float* w0 = (const float*)d_in[28];
    const float* b0 = (const float*)d_in[29];
    const float* w1 = (const float*)d_in[30];
    const float* b1 = (const float*)d_in[31];
    const float* wo = (const float*)d_in[32];
    const float* bo = (const float*)d_in[33];

    const int N = N_NODES;
    const size_t n128 = (size_t)N * 128;

    float* ws = (float*)d_ws;
    WsPtrs w;
    size_t off = 0;
    w.h      = ws + off;                       off += n128;
    w.ah0    = (__hip_bfloat16*)(ws + off);    off += (size_t)N * 208;
    w.ah1    = (__hip_bfloat16*)(ws + off);    off += (size_t)N * 208;
    w.G      = ws + off;                       off += 2 * n128;
    w.hb     = (uint*)(w.G + n128);            // second half of G
    w.r1b    = (__hip_bfloat16*)(ws + off);    off += n128 / 2;
    w.bfragB = (__hip_bfloat16*)(ws + off);    off += 9 * 16384 / 2;
    w.gruB   = (__hip_bfloat16*)(ws + off);    off += 512 * 288 / 2;
    w.roB    = (__hip_bfloat16*)(ws + off);    off += 256 * 288 / 2;
    w.gruBias = ws + off;                      off += 512;
    w.roBias  = ws + off;                      off += 256;
    w.indptr  = (int*)(ws + off);              off += KN_TOT + 8;
    w.cursor  = (int*)(ws + off);              off += KN_TOT;
    w.partial = (int*)(ws + off);              off += 4096;
    w.elist   = (int*)(ws + off);              off += E_TOT;
    w.pooled  = ws + off;                      off += 64 * 128;
    w.x1      = ws + off;                      off += 64 * 256;
    w.x2      = ws + off;                      off += 64 * 128;

    // ---- merged CSR build ----
    hipMemsetAsync(w.cursor, 0, KN_TOT * sizeof(int), stream);
    hist2_kernel<<<(E_TOT + 255) / 256, 256, 0, stream>>>(bi_dst, bi_et, knn_dst, knn_et, w.cursor);
    scan1_kernel<<<KN_TOT / 256, 256, 0, stream>>>(w.cursor, w.indptr, w.partial);
    scan2b_kernel<<<1, 256, 0, stream>>>(w.partial, KN_TOT / 256, w.indptr + KN_TOT, E_TOT);
    scan3c_kernel<<<KN_TOT / 256, 256, 0, stream>>>(w.indptr, w.partial, w.cursor);
    fill2_kernel<<<(E_TOT + 255) / 256, 256, 0, stream>>>(bi_src, bi_dst, bi_et,
                                                          knn_src, knn_dst, knn_et,
                                                          w.cursor, w.elist);

    // Stage 1: bond graph (5 etypes), Fin=64
    run_stage<5>(stream, feat, nullptr, 64, s1, w, w.indptr, nullptr, w.r1b);
    // Stage 2: knn graph (9 etypes), feat = stage-1 readout (bf16)
    float* rout2 = w.G;
    run_stage<9>(stream, nullptr, w.r1b, 128, s2, w, w.indptr + KN_BI, rout2, nullptr);

    // Stage 3: ligand pooling + MLP
    pool_kernel<<<64, 128, 0, stream>>>(rout2, w.pooled);
    {
        dim3 g1(1, 4);
        gemm_kernel<<<g1, 256, 0, stream>>>(w.pooled, 128, w0, 256, b0, w.x1, 256, 128, 1);
        dim3 g2(1, 2);
        gemm_kernel<<<g2, 256, 0, stream>>>(w.x1, 256, w1, 128, b1, w.x2, 128, 256, 1);
    }
    out_kernel<<<64, 64, 0, stream>>>(w.x2, wo, bo, (float*)d_out);
}

// Round 12
// 768.917 us; speedup vs baseline: 1.0419x; 1.0419x over previous
//
#include <hip/hip_runtime.h>
#include <hip/hip_bf16.h>

#define N_NODES 50176
#define PER 392
#define E_BI (N_NODES * 4)      // 200704
#define E_KNN (N_NODES * 16)    // 802816
#define E_TOT (E_BI + E_KNN)    // 1003520
#define KN_BI (N_NODES * 5)     // 250880
#define KN_TOT (N_NODES * 14)   // 702464
#define AH_S 416                // ah row stride (shorts): [a(128)|h(128)|cnt(32)|feat(128)]
#define AH_U 208                // ... in uints

typedef __attribute__((ext_vector_type(8))) short short8;
typedef __attribute__((ext_vector_type(4))) float float4v;
typedef unsigned int uint;
typedef unsigned short ushort;

__device__ __forceinline__ float sigmoidf_(float x) { return 1.f / (1.f + __expf(-x)); }
__device__ __forceinline__ ushort f2bu(float x) {
    __hip_bfloat16 t = __float2bfloat16(x);
    return *reinterpret_cast<ushort*>(&t);
}
__device__ __forceinline__ float blo(uint u) { return __uint_as_float(u << 16); }
__device__ __forceinline__ float bhi(uint u) { return __uint_as_float(u & 0xFFFF0000u); }

// ================= fused aggregate + per-etype transform (v4 + pairwise edge unroll) ===
// Block = 32 node rows, 256 threads: 8 threads/row (16 ch each, 2x16B loads/edge).
// Edges processed 2-at-a-time with independent registers (2x memory-level parallelism
// on the elist->hb dependent chain; thread shape / load width identical to v4).
template<int NET>
__global__ __launch_bounds__(256) void msg_kernel(
    const uint* __restrict__ hb,           // [N][64] uints (h bf16 packed)
    const int* __restrict__ indptr,        // [N*NET+1] slice (absolute into elist)
    const int* __restrict__ elist,
    const ushort* __restrict__ Bfrag,      // fragment-ordered weights
    ushort* __restrict__ aout)             // target ah buffer; write cols 0..127
{
    __shared__ ushort As[4][32][40];       // 10.25 KB, chunk-major, 80B rows
    const int tid = threadIdx.x;
    const int bm = blockIdx.x * 32;
    const int wave = tid >> 6, lane = tid & 63;
    const int quad = lane >> 4, lrow = lane & 15;
    const int wr = wave & 1, wc = wave >> 1;
    const int r = tid >> 3;                // node row 0..31
    const int oct = tid & 7;               // 16-ch group
    const int v = bm + r;

    uint* AsU = (uint*)As;                 // [ch][r][20] uints

    float4v acc[4] = {};

    for (int et = 0; et < NET; et++) {
        const int beg = indptr[v * NET + et], end = indptr[v * NET + et + 1];
        float av[16];
#pragma unroll
        for (int i = 0; i < 16; i++) av[i] = 0.f;

        int j = beg;
        for (; j + 2 <= end; j += 2) {
            int s0 = elist[j];
            int s1 = elist[j + 1];
            const uint4* p0 = (const uint4*)(hb + (size_t)s0 * 64 + oct * 8);
            const uint4* p1 = (const uint4*)(hb + (size_t)s1 * 64 + oct * 8);
            uint4 a0 = p0[0], a1 = p0[1];
            uint4 b0 = p1[0], b1 = p1[1];
            av[0] += blo(a0.x) + blo(b0.x); av[1] += bhi(a0.x) + bhi(b0.x);
            av[2] += blo(a0.y) + blo(b0.y); av[3] += bhi(a0.y) + bhi(b0.y);
            av[4] += blo(a0.z) + blo(b0.z); av[5] += bhi(a0.z) + bhi(b0.z);
            av[6] += blo(a0.w) + blo(b0.w); av[7] += bhi(a0.w) + bhi(b0.w);
            av[8]  += blo(a1.x) + blo(b1.x); av[9]  += bhi(a1.x) + bhi(b1.x);
            av[10] += blo(a1.y) + blo(b1.y); av[11] += bhi(a1.y) + bhi(b1.y);
            av[12] += blo(a1.z) + blo(b1.z); av[13] += bhi(a1.z) + bhi(b1.z);
            av[14] += blo(a1.w) + blo(b1.w); av[15] += bhi(a1.w) + bhi(b1.w);
        }
        if (j < end) {
            int src = elist[j];
            const uint4* hp = (const uint4*)(hb + (size_t)src * 64 + oct * 8);
            uint4 u0 = hp[0];
            uint4 u1 = hp[1];
            av[0] += blo(u0.x); av[1] += bhi(u0.x);
            av[2] += blo(u0.y); av[3] += bhi(u0.y);
            av[4] += blo(u0.z); av[5] += bhi(u0.z);
            av[6] += blo(u0.w); av[7] += bhi(u0.w);
            av[8]  += blo(u1.x); av[9]  += bhi(u1.x);
            av[10] += blo(u1.y); av[11] += bhi(u1.y);
            av[12] += blo(u1.z); av[13] += bhi(u1.z);
            av[14] += blo(u1.w); av[15] += bhi(u1.w);
        }

        __syncthreads();                   // previous etype's As reads complete
        {
            int base = ((oct >> 1) * 32 + r) * 20 + (oct & 1) * 8;
#pragma unroll
            for (int u = 0; u < 8; u++)
                AsU[base + u] = (uint)f2bu(av[2 * u]) | ((uint)f2bu(av[2 * u + 1]) << 16);
        }
        __syncthreads();

#pragma unroll
        for (int ch = 0; ch < 4; ch++) {
            short8 af = *(const short8*)&As[ch][wr * 16 + lrow][quad * 8];
            const ushort* bp = Bfrag + ((size_t)(((et * 4 + ch) * 2 + wc) * 4) << 9) + lane * 8;
#pragma unroll
            for (int j2 = 0; j2 < 4; j2++) {
                short8 bfr = *(const short8*)(bp + j2 * 512);
                acc[j2] = __builtin_amdgcn_mfma_f32_16x16x32_bf16(af, bfr, acc[j2], 0, 0, 0);
            }
        }
    }

#pragma unroll
    for (int j2 = 0; j2 < 4; j2++) {
        int col = wc * 64 + j2 * 16 + lrow;
#pragma unroll
        for (int rr = 0; rr < 4; rr++) {
            size_t row = (size_t)(bm + wr * 16 + quad * 4 + rr);
            aout[row * AH_S + col] = f2bu(acc[j2][rr]);
        }
    }
}

// ================= GRU GEMM with fused gate epilogue (ping-pong, race-free) ============
// h_old read as bf16 from ahIn h-cols (no fp32 h buffer).
__global__ __launch_bounds__(256) void gru_gemm_kernel(
    const ushort* __restrict__ A,          // ahIn base, lda AH_S
    const ushort* __restrict__ Bt,         // gruB [512][288] permuted
    const float* __restrict__ bias,        // [512] permuted
    ushort* __restrict__ ahOut, ushort* __restrict__ hbS)
{
    __shared__ ushort As[128 * 32];
    __shared__ ushort Bs[128 * 32];
    const int tid = threadIdx.x;
    const int bm = blockIdx.x * 128;
    const int bn = blockIdx.y * 128;
    const int wave = tid >> 6, lane = tid & 63;
    const int quad = lane >> 4, lrow = lane & 15;
    const int wr = wave & 1, wc = wave >> 1;

    float4v acc[4][4] = {};

    for (int k0 = 0; k0 < 288; k0 += 32) {
        __syncthreads();
#pragma unroll
        for (int p = 0; p < 2; p++) {
            int lin = p * 256 + tid;
            int r = lin >> 2;
            int kc = (lin & 3) * 8;
            *(short8*)&As[r * 32 + kc] = *(const short8*)(A + (size_t)(bm + r) * AH_S + k0 + kc);
            *(short8*)&Bs[r * 32 + kc] = *(const short8*)(Bt + (size_t)(bn + r) * 288 + k0 + kc);
        }
        __syncthreads();
        short8 af[4], bfr[4];
#pragma unroll
        for (int i = 0; i < 4; i++)
            af[i] = *(const short8*)&As[(wr * 64 + i * 16 + lrow) * 32 + quad * 8];
#pragma unroll
        for (int j = 0; j < 4; j++)
            bfr[j] = *(const short8*)&Bs[(wc * 64 + j * 16 + lrow) * 32 + quad * 8];
#pragma unroll
        for (int i = 0; i < 4; i++)
#pragma unroll
            for (int j = 0; j < 4; j++)
                acc[i][j] = __builtin_amdgcn_mfma_f32_16x16x32_bf16(af[i], bfr[j], acc[i][j], 0, 0, 0);
    }

    const int ch = (bn >> 7) * 32 + wc * 16 + lrow;
    const float b0 = bias[bn + wc * 64 + lrow];
    const float b1 = bias[bn + wc * 64 + 16 + lrow];
    const float b2 = bias[bn + wc * 64 + 32 + lrow];
    const float b3 = bias[bn + wc * 64 + 48 + lrow];
#pragma unroll
    for (int i = 0; i < 4; i++) {
#pragma unroll
        for (int r = 0; r < 4; r++) {
            size_t row = (size_t)(bm + wr * 64 + i * 16 + quad * 4 + r);
            float rr = sigmoidf_(acc[i][0][r] + b0);
            float zz = sigmoidf_(acc[i][1][r] + b1);
            float nn = tanhf(acc[i][2][r] + b2 + rr * (acc[i][3][r] + b3));
            float hold = __uint_as_float(((uint)A[row * AH_S + 128 + ch]) << 16);
            float hnew = (1.f - zz) * nn + zz * hold;
            ushort hu = f2bu(hnew);
            ahOut[row * AH_S + 128 + ch] = hu;
            hbS[row * 128 + ch] = hu;
        }
    }
}

// ================= readout GEMM with fused sigmoid-mul epilogue =================
__global__ __launch_bounds__(256) void ro_gemm_kernel(
    const ushort* __restrict__ A,
    const ushort* __restrict__ Bt,         // [256][288]
    const float* __restrict__ bias,        // [256] permuted
    ushort* __restrict__ rb)               // bf16 out [N,128]
{
    __shared__ ushort As[128 * 32];
    __shared__ ushort Bs[128 * 32];
    const int tid = threadIdx.x;
    const int bm = blockIdx.x * 128;
    const int bn = blockIdx.y * 128;
    const int wave = tid >> 6, lane = tid & 63;
    const int quad = lane >> 4, lrow = lane & 15;
    const int wr = wave & 1, wc = wave >> 1;

    float4v acc[4][4] = {};

    for (int k0 = 0; k0 < 288; k0 += 32) {
        __syncthreads();
#pragma unroll
        for (int p = 0; p < 2; p++) {
            int lin = p * 256 + tid;
            int r = lin >> 2;
            int kc = (lin & 3) * 8;
            *(short8*)&As[r * 32 + kc] = *(const short8*)(A + (size_t)(bm + r) * AH_S + k0 + kc);
            *(short8*)&Bs[r * 32 + kc] = *(const short8*)(Bt + (size_t)(bn + r) * 288 + k0 + kc);
        }
        __syncthreads();
        short8 af[4], bfr[4];
#pragma unroll
        for (int i = 0; i < 4; i++)
            af[i] = *(const short8*)&As[(wr * 64 + i * 16 + lrow) * 32 + quad * 8];
#pragma unroll
        for (int j = 0; j < 4; j++)
            bfr[j] = *(const short8*)&Bs[(wc * 64 + j * 16 + lrow) * 32 + quad * 8];
#pragma unroll
        for (int i = 0; i < 4; i++)
#pragma unroll
            for (int j = 0; j < 4; j++)
                acc[i][j] = __builtin_amdgcn_mfma_f32_16x16x32_bf16(af[i], bfr[j], acc[i][j], 0, 0, 0);
    }

    const int c0 = (bn >> 7) * 64 + wc * 32 + lrow;
    const int c1 = c0 + 16;
    const float bu0 = bias[bn + wc * 64 + lrow];
    const float bv0 = bias[bn + wc * 64 + 16 + lrow];
    const float bu1 = bias[bn + wc * 64 + 32 + lrow];
    const float bv1 = bias[bn + wc * 64 + 48 + lrow];
#pragma unroll
    for (int i = 0; i < 4; i++) {
#pragma unroll
        for (int r = 0; r < 4; r++) {
            size_t row = (size_t)(bm + wr * 64 + i * 16 + quad * 4 + r);
            float o0 = sigmoidf_(acc[i][0][r] + bu0) * (acc[i][1][r] + bv0);
            float o1 = sigmoidf_(acc[i][2][r] + bu1) * (acc[i][3][r] + bv1);
            rb[row * 128 + c0] = f2bu(o0);
            rb[row * 128 + c1] = f2bu(o1);
        }
    }
}

// ================= small fp32 GEMM (stage-3 MLP only) =================
__global__ __launch_bounds__(256) void gemm_kernel(
    const float* __restrict__ A, int lda,
    const float* __restrict__ B, int ldb,
    const float* __restrict__ bias,
    float* __restrict__ C, int ldc,
    int K, int act)
{
    __shared__ float As[32][68];
    __shared__ float Bs[32][68];
    const int tid = threadIdx.x;
    const int bm = blockIdx.x * 64;
    const int bn = blockIdx.y * 64;
    const int tm = (tid & 15) * 4;
    const int tn = (tid >> 4) * 4;
    float acc[4][4] = {};

    for (int k0 = 0; k0 < K; k0 += 32) {
#pragma unroll
        for (int p = 0; p < 2; p++) {
            int lin = p * 256 + tid;
            int ar = lin >> 3;
            int ac = (lin & 7) << 2;
            float4 av = *(const float4*)(A + (size_t)(bm + ar) * lda + (k0 + ac));
            As[ac + 0][ar] = av.x;
            As[ac + 1][ar] = av.y;
            As[ac + 2][ar] = av.z;
            As[ac + 3][ar] = av.w;
            int br = lin >> 4;
            int bc = (lin & 15) << 2;
            *(float4*)&Bs[br][bc] = *(const float4*)(B + (size_t)(k0 + br) * ldb + (bn + bc));
        }
        __syncthreads();
#pragma unroll
        for (int k = 0; k < 32; k++) {
            float4 a4 = *(const float4*)&As[k][tm];
            float4 b4 = *(const float4*)&Bs[k][tn];
            float av[4] = {a4.x, a4.y, a4.z, a4.w};
            float bv[4] = {b4.x, b4.y, b4.z, b4.w};
#pragma unroll
            for (int i = 0; i < 4; i++)
#pragma unroll
                for (int j = 0; j < 4; j++)
                    acc[i][j] += av[i] * bv[j];
        }
        __syncthreads();
    }
#pragma unroll
    for (int i = 0; i < 4; i++) {
        size_t row = (size_t)(bm + tm + i);
#pragma unroll
        for (int j = 0; j < 4; j++) {
            int col = bn + tn + j;
            float val = acc[i][j] + (bias ? bias[col] : 0.f);
            if (act == 1) val = fmaxf(val, 0.f);
            C[row * ldc + col] = val;
        }
    }
}

// ================= weight prep =================
__global__ void prep_bfrag_kernel(const float* __restrict__ W, __hip_bfloat16* __restrict__ Bf,
                                  int net)
{
    int idx = blockIdx.x * blockDim.x + threadIdx.x;   // net*16384
    int m = idx & 7;
    int lane = (idx >> 3) & 63;
    int f = idx >> 9;
    int j = f & 3; f >>= 2;
    int wc = f & 1; f >>= 1;
    int ch = f & 3;
    int et = f >> 2;
    int quad = lane >> 4, lrow = lane & 15;
    int k = ch * 32 + quad * 8 + m;
    int c = wc * 64 + j * 16 + lrow;
    Bf[idx] = __float2bfloat16(W[et * 16384 + k * 128 + c]);
}

__global__ void prep_gru_kernel(const float* __restrict__ wih, const float* __restrict__ whh,
                                const float* __restrict__ bih, const float* __restrict__ bhh,
                                const float* __restrict__ b, int net,
                                __hip_bfloat16* __restrict__ Bt, float* __restrict__ bias)
{
    int idx = blockIdx.x * blockDim.x + threadIdx.x;   // 512*288
    int p = idx / 288;
    int k = idx - p * 288;
    int g = (p >> 4) & 3;
    int c = (p >> 7) * 32 + ((p >> 6) & 1) * 16 + (p & 15);
    float val = 0.f;
    if (k < 128) {                                     // from a
        if (g == 0)      val = wih[k * 384 + c];
        else if (g == 1) val = wih[k * 384 + 128 + c];
        else if (g == 2) val = wih[k * 384 + 256 + c];
    } else if (k < 256) {                              // from h
        int kk = k - 128;
        if (g == 0)      val = whh[kk * 384 + c];
        else if (g == 1) val = whh[kk * 384 + 128 + c];
        else if (g == 3) val = whh[kk * 384 + 256 + c];
    } else {                                           // cnt cols: b @ wih
        int j = k - 256;
        if (j < net && g < 3) {
            int col = g * 128 + c;
            float s = 0.f;
            for (int kk = 0; kk < 128; kk++) s += b[j * 128 + kk] * wih[kk * 384 + col];
            val = s;
        }
    }
    Bt[idx] = __float2bfloat16(val);
    if (k == 0) {
        float bv;
        if (g == 0)      bv = bih[c] + bhh[c];
        else if (g == 1) bv = bih[128 + c] + bhh[128 + c];
        else if (g == 2) bv = bih[256 + c];
        else             bv = bhh[256 + c];
        bias[p] = bv;
    }
}

__global__ void prep_ro_kernel(const float* __restrict__ iw, const float* __restrict__ jw,
                               const float* __restrict__ ib, const float* __restrict__ jb,
                               int Fin, __hip_bfloat16* __restrict__ Bt,
                               float* __restrict__ bias)
{
    int idx = blockIdx.x * blockDim.x + threadIdx.x;   // 256*288
    int p = idx / 288;
    int k = idx - p * 288;
    int j = (p >> 4) & 3;
    int s = j & 1;
    int c = ((p >> 7) & 1) * 64 + ((p >> 6) & 1) * 32 + (j >> 1) * 16 + (p & 15);
    float val = 0.f;
    if (k < 128) {
        val = s ? jw[k * 128 + c] : iw[k * 128 + c];
    } else if (k >= 160) {
        int kf = k - 160;
        if (kf < Fin && s == 0) val = iw[(128 + kf) * 128 + c];
    }
    Bt[idx] = __float2bfloat16(val);
    if (k == 0) bias[p] = s ? jb[c] : ib[c];
}

// ================= merged CSR build =================
__global__ void hist2_kernel(const int* __restrict__ bd, const int* __restrict__ be,
                             const int* __restrict__ kd, const int* __restrict__ ke,
                             int* __restrict__ counts)
{
    int e = blockIdx.x * blockDim.x + threadIdx.x;
    if (e >= E_TOT) return;
    if (e < E_BI) atomicAdd(&counts[bd[e] * 5 + be[e]], 1);
    else { int i = e - E_BI; atomicAdd(&counts[KN_BI + kd[i] * 9 + ke[i]], 1); }
}

__global__ void scan1_kernel(const int* __restrict__ counts, int* __restrict__ local_ex,
                             int* __restrict__ partial)
{
    __shared__ int s[256];
    int t = threadIdx.x;
    int i = blockIdx.x * 256 + t;
    int v = counts[i];
    s[t] = v;
    __syncthreads();
    for (int off = 1; off < 256; off <<= 1) {
        int x = 0;
        if (t >= off) x = s[t - off];
        __syncthreads();
        if (t >= off) s[t] += x;
        __syncthreads();
    }
    local_ex[i] = s[t] - v;
    if (t == 255) partial[blockIdx.x] = s[255];
}

__global__ void scan2b_kernel(int* __restrict__ partial, int nb, int* __restrict__ last, int E)
{
    __shared__ int s[256];
    int t = threadIdx.x;
    int loc[11];
    int sum = 0;
#pragma unroll
    for (int q = 0; q < 11; q++) {
        int idx = t * 11 + q;
        int v = (idx < nb) ? partial[idx] : 0;
        loc[q] = sum; sum += v;
    }
    s[t] = sum;
    __syncthreads();
    for (int off = 1; off < 256; off <<= 1) {
        int x = 0;
        if (t >= off) x = s[t - off];
        __syncthreads();
        if (t >= off) s[t] += x;
        __syncthreads();
    }
    int excl = s[t] - sum;
#pragma unroll
    for (int q = 0; q < 11; q++) {
        int idx = t * 11 + q;
        if (idx < nb) partial[idx] = excl + loc[q];
    }
    if (t == 0) *last = E;
}

__global__ void scan3c_kernel(int* __restrict__ indptr, const int* __restrict__ partial,
                              int* __restrict__ cursor)
{
    int i = blockIdx.x * 256 + threadIdx.x;
    int v = indptr[i] + partial[blockIdx.x];
    indptr[i] = v;
    cursor[i] = v;
}

__global__ void fill2_kernel(const int* __restrict__ bs, const int* __restrict__ bd,
                             const int* __restrict__ be,
                             const int* __restrict__ ks, const int* __restrict__ kd,
                             const int* __restrict__ ke,
                             int* __restrict__ cursor, int* __restrict__ elist)
{
    int e = blockIdx.x * blockDim.x + threadIdx.x;
    if (e >= E_TOT) return;
    if (e < E_BI) {
        int pos = atomicAdd(&cursor[bd[e] * 5 + be[e]], 1);
        elist[pos] = bs[e];
    } else {
        int i = e - E_BI;
        int pos = atomicAdd(&cursor[KN_BI + kd[i] * 9 + ke[i]], 1);
        elist[pos] = ks[i];
    }
}

// ================= elementwise: pad + cnt fused (no fp32 h) =================
__global__ void pad_cnt_kernel(const float* __restrict__ fsrc, const ushort* __restrict__ bsrc,
                               const int* __restrict__ indptr, int net,
                               uint* __restrict__ ahA, uint* __restrict__ ahB,
                               uint* __restrict__ hb, int Fin)
{
    int idx = blockIdx.x * blockDim.x + threadIdx.x;   // N*32
    int v = idx >> 5;
    int j = idx & 31;
    int c = j * 4;
    float4 val = make_float4(0.f, 0.f, 0.f, 0.f);
    if (bsrc) {
        uint2 u = *(const uint2*)(bsrc + (size_t)v * Fin + c);
        val.x = blo(u.x); val.y = bhi(u.x);
        val.z = blo(u.y); val.w = bhi(u.y);
    } else if (c < Fin) {
        val = *(const float4*)(fsrc + (size_t)v * Fin + c);
    }
    uint2 pk;
    pk.x = (uint)f2bu(val.x) | ((uint)f2bu(val.y) << 16);
    pk.y = (uint)f2bu(val.z) | ((uint)f2bu(val.w) << 16);
    *(uint2*)(ahA + (size_t)v * AH_U + 64 + c / 2) = pk;    // h cols (step-0 input)
    *(uint2*)(ahA + (size_t)v * AH_U + 144 + c / 2) = pk;   // feat cols
    *(uint2*)(ahB + (size_t)v * AH_U + 144 + c / 2) = pk;
    *(uint2*)(hb + (size_t)v * 64 + c / 2) = pk;
    float cv = 0.f;
    if (j < net) cv = (float)(indptr[v * net + j + 1] - indptr[v * net + j]);
    ushort u = f2bu(cv);
    ((ushort*)ahA)[(size_t)v * AH_S + 256 + j] = u;
    ((ushort*)ahB)[(size_t)v * AH_S + 256 + j] = u;
}

// pool from bf16 readout
__global__ void pool_kernel(const ushort* __restrict__ r2, float* __restrict__ pooled)
{
    int s = blockIdx.x;
    int c = threadIdx.x;
    const ushort* base = r2 + (size_t)(2 * s) * PER * 128;
    float acc = 0.f;
    for (int i = 0; i < PER; i++)
        acc += __uint_as_float(((uint)base[(size_t)i * 128 + c]) << 16);
    pooled[s * 128 + c] = acc;
}

__global__ void out_kernel(const float* __restrict__ x2, const float* __restrict__ wo,
                           const float* __restrict__ bo, float* __restrict__ out)
{
    int row = blockIdx.x;
    int t = threadIdx.x;
    float s = x2[row * 128 + t] * wo[t] + x2[row * 128 + 64 + t] * wo[64 + t];
#pragma unroll
    for (int off = 32; off; off >>= 1) s += __shfl_down(s, off);
    if (t == 0) out[row] = s + bo[0];
}

struct GGParams {
    const float *W, *b, *wih, *whh, *bih, *bhh, *iw, *ib, *jw, *jb;
};

struct WsPtrs {
    __hip_bfloat16 *ah0, *ah1;   // [N,416] bf16 ping-pong
    float* G;                    // 2*n128 floats: r2b (bf16) | hb
    uint* hb;
    __hip_bfloat16* r1b;
    __hip_bfloat16 *bfragB, *gruB, *roB;
    float *gruBias, *roBias;
    int *indptr, *cursor, *partial, *elist;
    float *pooled, *x1, *x2;
};

template<int NET>
static void run_stage(hipStream_t st, const float* featF, const __hip_bfloat16* featB, int Fin,
                      const GGParams& p, const WsPtrs& w, const int* indptr_slice,
                      __hip_bfloat16* rout_b)
{
    const int N = N_NODES;
    ushort* ahA = (ushort*)w.ah0;
    ushort* ahB = (ushort*)w.ah1;
    ushort* hbS = (ushort*)w.hb;

    prep_bfrag_kernel<<<(NET * 16384) / 256, 256, 0, st>>>(p.W, w.bfragB, NET);
    prep_gru_kernel<<<(512 * 288) / 256, 256, 0, st>>>(p.wih, p.whh, p.bih, p.bhh, p.b, NET,
                                                       w.gruB, w.gruBias);
    prep_ro_kernel<<<(256 * 288) / 256, 256, 0, st>>>(p.iw, p.jw, p.ib, p.jb, Fin,
                                                      w.roB, w.roBias);

    pad_cnt_kernel<<<(N * 32) / 256, 256, 0, st>>>(featF, (const ushort*)featB,
                                                   indptr_slice, NET,
                                                   (uint*)ahA, (uint*)ahB, w.hb, Fin);

    ushort* ahIn = ahA;
    ushort* ahOut = ahB;
    for (int step = 0; step < 2; step++) {
        msg_kernel<NET><<<N / 32, 256, 0, st>>>(w.hb, indptr_slice, w.elist,
                                                (ushort*)w.bfragB, ahIn);
        dim3 g(N / 128, 4);
        gru_gemm_kernel<<<g, 256, 0, st>>>(ahIn, (ushort*)w.gruB, w.gruBias, ahOut, hbS);
        ushort* t = ahIn; ahIn = ahOut; ahOut = t;
    }
    dim3 gr(N / 128, 2);
    ro_gemm_kernel<<<gr, 256, 0, st>>>(ahIn + 128, (ushort*)w.roB, w.roBias,
                                       (ushort*)rout_b);
}

extern "C" void kernel_launch(void* const* d_in, const int* in_sizes, int n_in,
                              void* d_out, int out_size, void* d_ws, size_t ws_size,
                              hipStream_t stream)
{
    const float* feat    = (const float*)d_in[0];
    const int*   bi_src  = (const int*)d_in[1];
    const int*   bi_dst  = (const int*)d_in[2];
    const int*   bi_et   = (const int*)d_in[3];
    const int*   knn_src = (const int*)d_in[4];
    const int*   knn_dst = (const int*)d_in[5];
    const int*   knn_et  = (const int*)d_in[6];

    GGParams s1 { (const float*)d_in[8],  (const float*)d_in[9],  (const float*)d_in[10],
                  (const float*)d_in[11], (const float*)d_in[12], (const float*)d_in[13],
                  (const float*)d_in[14], (const float*)d_in[15], (const float*)d_in[16],
                  (const float*)d_in[17] };
    GGParams s2 { (const float*)d_in[18], (const float*)d_in[19], (const float*)d_in[20],
                  (const float*)d_in[21], (const float*)d_in[22], (const float*)d_in[23],
                  (const float*)d_in[24], (const float*)d_in[25], (const float*)d_in[26],
                  (const float*)d_in[27] };
    const float* w0 = (const float*)d_in[28];
    const float* b0 = (const float*)d_in[29];
    const float* w1 = (const float*)d_in[30];
    const float* b1 = (const float*)d_in[31];
    const float* wo = (const float*)d_in[32];
    const float* bo = (const float*)d_in[33];

    const int N = N_NODES;
    const size_t n128 = (size_t)N * 128;

    float* ws = (float*)d_ws;
    WsPtrs w;
    size_t off = 0;
    w.ah0    = (__hip_bfloat16*)(ws + off);    off += (size_t)N * 208;
    w.ah1    = (__hip_bfloat16*)(ws + off);    off += (size_t)N * 208;
    w.G      = ws + off;                       off += 2 * n128;
    w.hb     = (uint*)(w.G + n128);            // second half of G
    w.r1b    = (__hip_bfloat16*)(ws + off);    off += n128 / 2;
    w.bfragB = (__hip_bfloat16*)(ws + off);    off += 9 * 16384 / 2;
    w.gruB   = (__hip_bfloat16*)(ws + off);    off += 512 * 288 / 2;
    w.roB    = (__hip_bfloat16*)(ws + off);    off += 256 * 288 / 2;
    w.gruBias = ws + off;                      off += 512;
    w.roBias  = ws + off;                      off += 256;
    w.indptr  = (int*)(ws + off);              off += KN_TOT + 8;
    w.cursor  = (int*)(ws + off);              off += KN_TOT;
    w.partial = (int*)(ws + off);              off += 4096;
    w.elist   = (int*)(ws + off);              off += E_TOT;
    w.pooled  = ws + off;                      off += 64 * 128;
    w.x1      = ws + off;                      off += 64 * 256;
    w.x2      = ws + off;                      off += 64 * 128;

    // ---- merged CSR build ----
    hipMemsetAsync(w.cursor, 0, KN_TOT * sizeof(int), stream);
    hist2_kernel<<<(E_TOT + 255) / 256, 256, 0, stream>>>(bi_dst, bi_et, knn_dst, knn_et, w.cursor);
    scan1_kernel<<<KN_TOT / 256, 256, 0, stream>>>(w.cursor, w.indptr, w.partial);
    scan2b_kernel<<<1, 256, 0, stream>>>(w.partial, KN_TOT / 256, w.indptr + KN_TOT, E_TOT);
    scan3c_kernel<<<KN_TOT / 256, 256, 0, stream>>>(w.indptr, w.partial, w.cursor);
    fill2_kernel<<<(E_TOT + 255) / 256, 256, 0, stream>>>(bi_src, bi_dst, bi_et,
                                                          knn_src, knn_dst, knn_et,
                                                          w.cursor, w.elist);

    // Stage 1: bond graph (5 etypes), Fin=64
    run_stage<5>(stream, feat, nullptr, 64, s1, w, w.indptr, w.r1b);
    // Stage 2: knn graph (9 etypes), feat = stage-1 readout (bf16)
    __hip_bfloat16* r2b = (__hip_bfloat16*)w.G;   // first half of G
    run_stage<9>(stream, nullptr, w.r1b, 128, s2, w, w.indptr + KN_BI, r2b);

    // Stage 3: ligand pooling + MLP
    pool_kernel<<<64, 128, 0, stream>>>((const ushort*)r2b, w.pooled);
    {
        dim3 g1(1, 4);
        gemm_kernel<<<g1, 256, 0, stream>>>(w.pooled, 128, w0, 256, b0, w.x1, 256, 128, 1);
        dim3 g2(1, 2);
        gemm_kernel<<<g2, 256, 0, stream>>>(w.x1, 256, w1, 128, b1, w.x2, 128, 256, 1);
    }
    out_kernel<<<64, 64, 0, stream>>>(w.x2, wo, bo, (float*)d_out);
}

// Round 13
// 731.170 us; speedup vs baseline: 1.0957x; 1.0516x over previous
//
#include <hip/hip_runtime.h>
#include <hip/hip_bf16.h>

#define N_NODES 50176
#define PER 392
#define E_BI (N_NODES * 4)      // 200704
#define E_KNN (N_NODES * 16)    // 802816
#define E_TOT (E_BI + E_KNN)    // 1003520
#define KN_BI (N_NODES * 5)     // 250880
#define KN_TOT (N_NODES * 14)   // 702464
#define AH_S 416                // ah row stride (shorts): [a(128)|h(128)|cnt(32)|feat(128)]
#define AH_U 208                // ... in uints

typedef __attribute__((ext_vector_type(8))) short short8;
typedef __attribute__((ext_vector_type(4))) float float4v;
typedef unsigned int uint;
typedef unsigned short ushort;

__device__ __forceinline__ float sigmoidf_(float x) { return 1.f / (1.f + __expf(-x)); }
__device__ __forceinline__ ushort f2bu(float x) {
    __hip_bfloat16 t = __float2bfloat16(x);
    return *reinterpret_cast<ushort*>(&t);
}
__device__ __forceinline__ float blo(uint u) { return __uint_as_float(u << 16); }
__device__ __forceinline__ float bhi(uint u) { return __uint_as_float(u & 0xFFFF0000u); }

// ================= fused aggregate + per-etype transform (v4 — measured optimum) ======
// Block = 32 node rows, 256 threads: 8 threads/row (16 ch each, 2x16B loads/edge).
// NOTE: r8 (thread reshape), r11 (parity split), r12 (pairwise unroll) all regressed
// vs this exact loop body — do not reshape the gather.
template<int NET>
__global__ __launch_bounds__(256) void msg_kernel(
    const uint* __restrict__ hb,           // [N][64] uints (h bf16 packed)
    const int* __restrict__ indptr,        // [N*NET+1] slice (absolute into elist)
    const int* __restrict__ elist,
    const ushort* __restrict__ Bfrag,      // fragment-ordered weights
    ushort* __restrict__ aout)             // target ah buffer; write cols 0..127
{
    __shared__ ushort As[4][32][40];       // 10.25 KB, chunk-major, 80B rows
    const int tid = threadIdx.x;
    const int bm = blockIdx.x * 32;
    const int wave = tid >> 6, lane = tid & 63;
    const int quad = lane >> 4, lrow = lane & 15;
    const int wr = wave & 1, wc = wave >> 1;
    const int r = tid >> 3;                // node row 0..31
    const int oct = tid & 7;               // 16-ch group
    const int v = bm + r;

    uint* AsU = (uint*)As;                 // [ch][r][20] uints

    float4v acc[4] = {};

    for (int et = 0; et < NET; et++) {
        const int beg = indptr[v * NET + et], end = indptr[v * NET + et + 1];
        float av[16];
#pragma unroll
        for (int i = 0; i < 16; i++) av[i] = 0.f;

        for (int j = beg; j < end; j++) {
            int src = elist[j];
            const uint4* hp = (const uint4*)(hb + (size_t)src * 64 + oct * 8);
            uint4 u0 = hp[0];
            uint4 u1 = hp[1];
            av[0] += blo(u0.x); av[1] += bhi(u0.x);
            av[2] += blo(u0.y); av[3] += bhi(u0.y);
            av[4] += blo(u0.z); av[5] += bhi(u0.z);
            av[6] += blo(u0.w); av[7] += bhi(u0.w);
            av[8]  += blo(u1.x); av[9]  += bhi(u1.x);
            av[10] += blo(u1.y); av[11] += bhi(u1.y);
            av[12] += blo(u1.z); av[13] += bhi(u1.z);
            av[14] += blo(u1.w); av[15] += bhi(u1.w);
        }

        __syncthreads();                   // previous etype's As reads complete
        {
            int base = ((oct >> 1) * 32 + r) * 20 + (oct & 1) * 8;
#pragma unroll
            for (int u = 0; u < 8; u++)
                AsU[base + u] = (uint)f2bu(av[2 * u]) | ((uint)f2bu(av[2 * u + 1]) << 16);
        }
        __syncthreads();

#pragma unroll
        for (int ch = 0; ch < 4; ch++) {
            short8 af = *(const short8*)&As[ch][wr * 16 + lrow][quad * 8];
            const ushort* bp = Bfrag + ((size_t)(((et * 4 + ch) * 2 + wc) * 4) << 9) + lane * 8;
#pragma unroll
            for (int j2 = 0; j2 < 4; j2++) {
                short8 bfr = *(const short8*)(bp + j2 * 512);
                acc[j2] = __builtin_amdgcn_mfma_f32_16x16x32_bf16(af, bfr, acc[j2], 0, 0, 0);
            }
        }
    }

#pragma unroll
    for (int j2 = 0; j2 < 4; j2++) {
        int col = wc * 64 + j2 * 16 + lrow;
#pragma unroll
        for (int rr = 0; rr < 4; rr++) {
            size_t row = (size_t)(bm + wr * 16 + quad * 4 + rr);
            aout[row * AH_S + col] = f2bu(acc[j2][rr]);
        }
    }
}

// ================= GRU GEMM with fused gate epilogue (ping-pong, race-free) ============
// h_old read as bf16 from ahIn h-cols (no fp32 h buffer).
__global__ __launch_bounds__(256) void gru_gemm_kernel(
    const ushort* __restrict__ A,          // ahIn base, lda AH_S
    const ushort* __restrict__ Bt,         // gruB [512][288] permuted
    const float* __restrict__ bias,        // [512] permuted
    ushort* __restrict__ ahOut, ushort* __restrict__ hbS)
{
    __shared__ ushort As[128 * 32];
    __shared__ ushort Bs[128 * 32];
    const int tid = threadIdx.x;
    const int bm = blockIdx.x * 128;
    const int bn = blockIdx.y * 128;
    const int wave = tid >> 6, lane = tid & 63;
    const int quad = lane >> 4, lrow = lane & 15;
    const int wr = wave & 1, wc = wave >> 1;

    float4v acc[4][4] = {};

    for (int k0 = 0; k0 < 288; k0 += 32) {
        __syncthreads();
#pragma unroll
        for (int p = 0; p < 2; p++) {
            int lin = p * 256 + tid;
            int r = lin >> 2;
            int kc = (lin & 3) * 8;
            *(short8*)&As[r * 32 + kc] = *(const short8*)(A + (size_t)(bm + r) * AH_S + k0 + kc);
            *(short8*)&Bs[r * 32 + kc] = *(const short8*)(Bt + (size_t)(bn + r) * 288 + k0 + kc);
        }
        __syncthreads();
        short8 af[4], bfr[4];
#pragma unroll
        for (int i = 0; i < 4; i++)
            af[i] = *(const short8*)&As[(wr * 64 + i * 16 + lrow) * 32 + quad * 8];
#pragma unroll
        for (int j = 0; j < 4; j++)
            bfr[j] = *(const short8*)&Bs[(wc * 64 + j * 16 + lrow) * 32 + quad * 8];
#pragma unroll
        for (int i = 0; i < 4; i++)
#pragma unroll
            for (int j = 0; j < 4; j++)
                acc[i][j] = __builtin_amdgcn_mfma_f32_16x16x32_bf16(af[i], bfr[j], acc[i][j], 0, 0, 0);
    }

    const int ch = (bn >> 7) * 32 + wc * 16 + lrow;
    const float b0 = bias[bn + wc * 64 + lrow];
    const float b1 = bias[bn + wc * 64 + 16 + lrow];
    const float b2 = bias[bn + wc * 64 + 32 + lrow];
    const float b3 = bias[bn + wc * 64 + 48 + lrow];
#pragma unroll
    for (int i = 0; i < 4; i++) {
#pragma unroll
        for (int r = 0; r < 4; r++) {
            size_t row = (size_t)(bm + wr * 64 + i * 16 + quad * 4 + r);
            float rr = sigmoidf_(acc[i][0][r] + b0);
            float zz = sigmoidf_(acc[i][1][r] + b1);
            float nn = tanhf(acc[i][2][r] + b2 + rr * (acc[i][3][r] + b3));
            float hold = __uint_as_float(((uint)A[row * AH_S + 128 + ch]) << 16);
            float hnew = (1.f - zz) * nn + zz * hold;
            ushort hu = f2bu(hnew);
            ahOut[row * AH_S + 128 + ch] = hu;
            hbS[row * 128 + ch] = hu;
        }
    }
}

// ================= readout GEMM with fused sigmoid-mul epilogue =================
__global__ __launch_bounds__(256) void ro_gemm_kernel(
    const ushort* __restrict__ A,
    const ushort* __restrict__ Bt,         // [256][288]
    const float* __restrict__ bias,        // [256] permuted
    ushort* __restrict__ rb)               // bf16 out [N,128]
{
    __shared__ ushort As[128 * 32];
    __shared__ ushort Bs[128 * 32];
    const int tid = threadIdx.x;
    const int bm = blockIdx.x * 128;
    const int bn = blockIdx.y * 128;
    const int wave = tid >> 6, lane = tid & 63;
    const int quad = lane >> 4, lrow = lane & 15;
    const int wr = wave & 1, wc = wave >> 1;

    float4v acc[4][4] = {};

    for (int k0 = 0; k0 < 288; k0 += 32) {
        __syncthreads();
#pragma unroll
        for (int p = 0; p < 2; p++) {
            int lin = p * 256 + tid;
            int r = lin >> 2;
            int kc = (lin & 3) * 8;
            *(short8*)&As[r * 32 + kc] = *(const short8*)(A + (size_t)(bm + r) * AH_S + k0 + kc);
            *(short8*)&Bs[r * 32 + kc] = *(const short8*)(Bt + (size_t)(bn + r) * 288 + k0 + kc);
        }
        __syncthreads();
        short8 af[4], bfr[4];
#pragma unroll
        for (int i = 0; i < 4; i++)
            af[i] = *(const short8*)&As[(wr * 64 + i * 16 + lrow) * 32 + quad * 8];
#pragma unroll
        for (int j = 0; j < 4; j++)
            bfr[j] = *(const short8*)&Bs[(wc * 64 + j * 16 + lrow) * 32 + quad * 8];
#pragma unroll
        for (int i = 0; i < 4; i++)
#pragma unroll
            for (int j = 0; j < 4; j++)
                acc[i][j] = __builtin_amdgcn_mfma_f32_16x16x32_bf16(af[i], bfr[j], acc[i][j], 0, 0, 0);
    }

    const int c0 = (bn >> 7) * 64 + wc * 32 + lrow;
    const int c1 = c0 + 16;
    const float bu0 = bias[bn + wc * 64 + lrow];
    const float bv0 = bias[bn + wc * 64 + 16 + lrow];
    const float bu1 = bias[bn + wc * 64 + 32 + lrow];
    const float bv1 = bias[bn + wc * 64 + 48 + lrow];
#pragma unroll
    for (int i = 0; i < 4; i++) {
#pragma unroll
        for (int r = 0; r < 4; r++) {
            size_t row = (size_t)(bm + wr * 64 + i * 16 + quad * 4 + r);
            float o0 = sigmoidf_(acc[i][0][r] + bu0) * (acc[i][1][r] + bv0);
            float o1 = sigmoidf_(acc[i][2][r] + bu1) * (acc[i][3][r] + bv1);
            rb[row * 128 + c0] = f2bu(o0);
            rb[row * 128 + c1] = f2bu(o1);
        }
    }
}

// ================= small fp32 GEMM (stage-3 MLP only) =================
__global__ __launch_bounds__(256) void gemm_kernel(
    const float* __restrict__ A, int lda,
    const float* __restrict__ B, int ldb,
    const float* __restrict__ bias,
    float* __restrict__ C, int ldc,
    int K, int act)
{
    __shared__ float As[32][68];
    __shared__ float Bs[32][68];
    const int tid = threadIdx.x;
    const int bm = blockIdx.x * 64;
    const int bn = blockIdx.y * 64;
    const int tm = (tid & 15) * 4;
    const int tn = (tid >> 4) * 4;
    float acc[4][4] = {};

    for (int k0 = 0; k0 < K; k0 += 32) {
#pragma unroll
        for (int p = 0; p < 2; p++) {
            int lin = p * 256 + tid;
            int ar = lin >> 3;
            int ac = (lin & 7) << 2;
            float4 av = *(const float4*)(A + (size_t)(bm + ar) * lda + (k0 + ac));
            As[ac + 0][ar] = av.x;
            As[ac + 1][ar] = av.y;
            As[ac + 2][ar] = av.z;
            As[ac + 3][ar] = av.w;
            int br = lin >> 4;
            int bc = (lin & 15) << 2;
            *(float4*)&Bs[br][bc] = *(const float4*)(B + (size_t)(k0 + br) * ldb + (bn + bc));
        }
        __syncthreads();
#pragma unroll
        for (int k = 0; k < 32; k++) {
            float4 a4 = *(const float4*)&As[k][tm];
            float4 b4 = *(const float4*)&Bs[k][tn];
            float av[4] = {a4.x, a4.y, a4.z, a4.w};
            float bv[4] = {b4.x, b4.y, b4.z, b4.w};
#pragma unroll
            for (int i = 0; i < 4; i++)
#pragma unroll
                for (int j = 0; j < 4; j++)
                    acc[i][j] += av[i] * bv[j];
        }
        __syncthreads();
    }
#pragma unroll
    for (int i = 0; i < 4; i++) {
        size_t row = (size_t)(bm + tm + i);
#pragma unroll
        for (int j = 0; j < 4; j++) {
            int col = bn + tn + j;
            float val = acc[i][j] + (bias ? bias[col] : 0.f);
            if (act == 1) val = fmaxf(val, 0.f);
            C[row * ldc + col] = val;
        }
    }
}

// ================= weight prep =================
__global__ void prep_bfrag_kernel(const float* __restrict__ W, __hip_bfloat16* __restrict__ Bf,
                                  int net)
{
    int idx = blockIdx.x * blockDim.x + threadIdx.x;   // net*16384
    int m = idx & 7;
    int lane = (idx >> 3) & 63;
    int f = idx >> 9;
    int j = f & 3; f >>= 2;
    int wc = f & 1; f >>= 1;
    int ch = f & 3;
    int et = f >> 2;
    int quad = lane >> 4, lrow = lane & 15;
    int k = ch * 32 + quad * 8 + m;
    int c = wc * 64 + j * 16 + lrow;
    Bf[idx] = __float2bfloat16(W[et * 16384 + k * 128 + c]);
}

__global__ void prep_gru_kernel(const float* __restrict__ wih, const float* __restrict__ whh,
                                const float* __restrict__ bih, const float* __restrict__ bhh,
                                const float* __restrict__ b, int net,
                                __hip_bfloat16* __restrict__ Bt, float* __restrict__ bias)
{
    int idx = blockIdx.x * blockDim.x + threadIdx.x;   // 512*288
    int p = idx / 288;
    int k = idx - p * 288;
    int g = (p >> 4) & 3;
    int c = (p >> 7) * 32 + ((p >> 6) & 1) * 16 + (p & 15);
    float val = 0.f;
    if (k < 128) {                                     // from a
        if (g == 0)      val = wih[k * 384 + c];
        else if (g == 1) val = wih[k * 384 + 128 + c];
        else if (g == 2) val = wih[k * 384 + 256 + c];
    } else if (k < 256) {                              // from h
        int kk = k - 128;
        if (g == 0)      val = whh[kk * 384 + c];
        else if (g == 1) val = whh[kk * 384 + 128 + c];
        else if (g == 3) val = whh[kk * 384 + 256 + c];
    } else {                                           // cnt cols: b @ wih
        int j = k - 256;
        if (j < net && g < 3) {
            int col = g * 128 + c;
            float s = 0.f;
            for (int kk = 0; kk < 128; kk++) s += b[j * 128 + kk] * wih[kk * 384 + col];
            val = s;
        }
    }
    Bt[idx] = __float2bfloat16(val);
    if (k == 0) {
        float bv;
        if (g == 0)      bv = bih[c] + bhh[c];
        else if (g == 1) bv = bih[128 + c] + bhh[128 + c];
        else if (g == 2) bv = bih[256 + c];
        else             bv = bhh[256 + c];
        bias[p] = bv;
    }
}

__global__ void prep_ro_kernel(const float* __restrict__ iw, const float* __restrict__ jw,
                               const float* __restrict__ ib, const float* __restrict__ jb,
                               int Fin, __hip_bfloat16* __restrict__ Bt,
                               float* __restrict__ bias)
{
    int idx = blockIdx.x * blockDim.x + threadIdx.x;   // 256*288
    int p = idx / 288;
    int k = idx - p * 288;
    int j = (p >> 4) & 3;
    int s = j & 1;
    int c = ((p >> 7) & 1) * 64 + ((p >> 6) & 1) * 32 + (j >> 1) * 16 + (p & 15);
    float val = 0.f;
    if (k < 128) {
        val = s ? jw[k * 128 + c] : iw[k * 128 + c];
    } else if (k >= 160) {
        int kf = k - 160;
        if (kf < Fin && s == 0) val = iw[(128 + kf) * 128 + c];
    }
    Bt[idx] = __float2bfloat16(val);
    if (k == 0) bias[p] = s ? jb[c] : ib[c];
}

// ================= merged CSR build =================
__global__ void hist2_kernel(const int* __restrict__ bd, const int* __restrict__ be,
                             const int* __restrict__ kd, const int* __restrict__ ke,
                             int* __restrict__ counts)
{
    int e = blockIdx.x * blockDim.x + threadIdx.x;
    if (e >= E_TOT) return;
    if (e < E_BI) atomicAdd(&counts[bd[e] * 5 + be[e]], 1);
    else { int i = e - E_BI; atomicAdd(&counts[KN_BI + kd[i] * 9 + ke[i]], 1); }
}

__global__ void scan1_kernel(const int* __restrict__ counts, int* __restrict__ local_ex,
                             int* __restrict__ partial)
{
    __shared__ int s[256];
    int t = threadIdx.x;
    int i = blockIdx.x * 256 + t;
    int v = counts[i];
    s[t] = v;
    __syncthreads();
    for (int off = 1; off < 256; off <<= 1) {
        int x = 0;
        if (t >= off) x = s[t - off];
        __syncthreads();
        if (t >= off) s[t] += x;
        __syncthreads();
    }
    local_ex[i] = s[t] - v;
    if (t == 255) partial[blockIdx.x] = s[255];
}

__global__ void scan2b_kernel(int* __restrict__ partial, int nb, int* __restrict__ last, int E)
{
    __shared__ int s[256];
    int t = threadIdx.x;
    int loc[11];
    int sum = 0;
#pragma unroll
    for (int q = 0; q < 11; q++) {
        int idx = t * 11 + q;
        int v = (idx < nb) ? partial[idx] : 0;
        loc[q] = sum; sum += v;
    }
    s[t] = sum;
    __syncthreads();
    for (int off = 1; off < 256; off <<= 1) {
        int x = 0;
        if (t >= off) x = s[t - off];
        __syncthreads();
        if (t >= off) s[t] += x;
        __syncthreads();
    }
    int excl = s[t] - sum;
#pragma unroll
    for (int q = 0; q < 11; q++) {
        int idx = t * 11 + q;
        if (idx < nb) partial[idx] = excl + loc[q];
    }
    if (t == 0) *last = E;
}

__global__ void scan3c_kernel(int* __restrict__ indptr, const int* __restrict__ partial,
                              int* __restrict__ cursor)
{
    int i = blockIdx.x * 256 + threadIdx.x;
    int v = indptr[i] + partial[blockIdx.x];
    indptr[i] = v;
    cursor[i] = v;
}

__global__ void fill2_kernel(const int* __restrict__ bs, const int* __restrict__ bd,
                             const int* __restrict__ be,
                             const int* __restrict__ ks, const int* __restrict__ kd,
                             const int* __restrict__ ke,
                             int* __restrict__ cursor, int* __restrict__ elist)
{
    int e = blockIdx.x * blockDim.x + threadIdx.x;
    if (e >= E_TOT) return;
    if (e < E_BI) {
        int pos = atomicAdd(&cursor[bd[e] * 5 + be[e]], 1);
        elist[pos] = bs[e];
    } else {
        int i = e - E_BI;
        int pos = atomicAdd(&cursor[KN_BI + kd[i] * 9 + ke[i]], 1);
        elist[pos] = ks[i];
    }
}

// ================= elementwise: pad + cnt fused (no fp32 h) =================
__global__ void pad_cnt_kernel(const float* __restrict__ fsrc, const ushort* __restrict__ bsrc,
                               const int* __restrict__ indptr, int net,
                               uint* __restrict__ ahA, uint* __restrict__ ahB,
                               uint* __restrict__ hb, int Fin)
{
    int idx = blockIdx.x * blockDim.x + threadIdx.x;   // N*32
    int v = idx >> 5;
    int j = idx & 31;
    int c = j * 4;
    float4 val = make_float4(0.f, 0.f, 0.f, 0.f);
    if (bsrc) {
        uint2 u = *(const uint2*)(bsrc + (size_t)v * Fin + c);
        val.x = blo(u.x); val.y = bhi(u.x);
        val.z = blo(u.y); val.w = bhi(u.y);
    } else if (c < Fin) {
        val = *(const float4*)(fsrc + (size_t)v * Fin + c);
    }
    uint2 pk;
    pk.x = (uint)f2bu(val.x) | ((uint)f2bu(val.y) << 16);
    pk.y = (uint)f2bu(val.z) | ((uint)f2bu(val.w) << 16);
    *(uint2*)(ahA + (size_t)v * AH_U + 64 + c / 2) = pk;    // h cols (step-0 input)
    *(uint2*)(ahA + (size_t)v * AH_U + 144 + c / 2) = pk;   // feat cols
    *(uint2*)(ahB + (size_t)v * AH_U + 144 + c / 2) = pk;
    *(uint2*)(hb + (size_t)v * 64 + c / 2) = pk;
    float cv = 0.f;
    if (j < net) cv = (float)(indptr[v * net + j + 1] - indptr[v * net + j]);
    ushort u = f2bu(cv);
    ((ushort*)ahA)[(size_t)v * AH_S + 256 + j] = u;
    ((ushort*)ahB)[(size_t)v * AH_S + 256 + j] = u;
}

// pool from bf16 readout
__global__ void pool_kernel(const ushort* __restrict__ r2, float* __restrict__ pooled)
{
    int s = blockIdx.x;
    int c = threadIdx.x;
    const ushort* base = r2 + (size_t)(2 * s) * PER * 128;
    float acc = 0.f;
    for (int i = 0; i < PER; i++)
        acc += __uint_as_float(((uint)base[(size_t)i * 128 + c]) << 16);
    pooled[s * 128 + c] = acc;
}

__global__ void out_kernel(const float* __restrict__ x2, const float* __restrict__ wo,
                           const float* __restrict__ bo, float* __restrict__ out)
{
    int row = blockIdx.x;
    int t = threadIdx.x;
    float s = x2[row * 128 + t] * wo[t] + x2[row * 128 + 64 + t] * wo[64 + t];
#pragma unroll
    for (int off = 32; off; off >>= 1) s += __shfl_down(s, off);
    if (t == 0) out[row] = s + bo[0];
}

struct GGParams {
    const float *W, *b, *wih, *whh, *bih, *bhh, *iw, *ib, *jw, *jb;
};

struct WsPtrs {
    __hip_bfloat16 *ah0, *ah1;   // [N,416] bf16 ping-pong
    float* G;                    // 2*n128 floats: r2b (bf16) | hb
    uint* hb;
    __hip_bfloat16* r1b;
    __hip_bfloat16 *bfragB, *gruB, *roB;
    float *gruBias, *roBias;
    int *indptr, *cursor, *partial, *elist;
    float *pooled, *x1, *x2;
};

template<int NET>
static void run_stage(hipStream_t st, const float* featF, const __hip_bfloat16* featB, int Fin,
                      const GGParams& p, const WsPtrs& w, const int* indptr_slice,
                      __hip_bfloat16* rout_b)
{
    const int N = N_NODES;
    ushort* ahA = (ushort*)w.ah0;
    ushort* ahB = (ushort*)w.ah1;
    ushort* hbS = (ushort*)w.hb;

    prep_bfrag_kernel<<<(NET * 16384) / 256, 256, 0, st>>>(p.W, w.bfragB, NET);
    prep_gru_kernel<<<(512 * 288) / 256, 256, 0, st>>>(p.wih, p.whh, p.bih, p.bhh, p.b, NET,
                                                       w.gruB, w.gruBias);
    prep_ro_kernel<<<(256 * 288) / 256, 256, 0, st>>>(p.iw, p.jw, p.ib, p.jb, Fin,
                                                      w.roB, w.roBias);

    pad_cnt_kernel<<<(N * 32) / 256, 256, 0, st>>>(featF, (const ushort*)featB,
                                                   indptr_slice, NET,
                                                   (uint*)ahA, (uint*)ahB, w.hb, Fin);

    ushort* ahIn = ahA;
    ushort* ahOut = ahB;
    for (int step = 0; step < 2; step++) {
        msg_kernel<NET><<<N / 32, 256, 0, st>>>(w.hb, indptr_slice, w.elist,
                                                (ushort*)w.bfragB, ahIn);
        dim3 g(N / 128, 4);
        gru_gemm_kernel<<<g, 256, 0, st>>>(ahIn, (ushort*)w.gruB, w.gruBias, ahOut, hbS);
        ushort* t = ahIn; ahIn = ahOut; ahOut = t;
    }
    dim3 gr(N / 128, 2);
    ro_gemm_kernel<<<gr, 256, 0, st>>>(ahIn + 128, (ushort*)w.roB, w.roBias,
                                       (ushort*)rout_b);
}

extern "C" void kernel_launch(void* const* d_in, const int* in_sizes, int n_in,
                              void* d_out, int out_size, void* d_ws, size_t ws_size,
                              hipStream_t stream)
{
    const float* feat    = (const float*)d_in[0];
    const int*   bi_src  = (const int*)d_in[1];
    const int*   bi_dst  = (const int*)d_in[2];
    const int*   bi_et   = (const int*)d_in[3];
    const int*   knn_src = (const int*)d_in[4];
    const int*   knn_dst = (const int*)d_in[5];
    const int*   knn_et  = (const int*)d_in[6];

    GGParams s1 { (const float*)d_in[8],  (const float*)d_in[9],  (const float*)d_in[10],
                  (const float*)d_in[11], (const float*)d_in[12], (const float*)d_in[13],
                  (const float*)d_in[14], (const float*)d_in[15], (const float*)d_in[16],
                  (const float*)d_in[17] };
    GGParams s2 { (const float*)d_in[18], (const float*)d_in[19], (const float*)d_in[20],
                  (const float*)d_in[21], (const float*)d_in[22], (const float*)d_in[23],
                  (const float*)d_in[24], (const float*)d_in[25], (const float*)d_in[26],
                  (const float*)d_in[27] };
    const float* w0 = (const float*)d_in[28];
    const float* b0 = (const float*)d_in[29];
    const float* w1 = (const float*)d_in[30];
    const float* b1 = (const float*)d_in[31];
    const float* wo = (const float*)d_in[32];
    const float* bo = (const float*)d_in[33];

    const int N = N_NODES;
    const size_t n128 = (size_t)N * 128;

    float* ws = (float*)d_ws;
    WsPtrs w;
    size_t off = 0;
    w.ah0    = (__hip_bfloat16*)(ws + off);    off += (size_t)N * 208;
    w.ah1    = (__hip_bfloat16*)(ws + off);    off += (size_t)N * 208;
    w.G      = ws + off;                       off += 2 * n128;
    w.hb     = (uint*)(w.G + n128);            // second half of G
    w.r1b    = (__hip_bfloat16*)(ws + off);    off += n128 / 2;
    w.bfragB = (__hip_bfloat16*)(ws + off);    off += 9 * 16384 / 2;
    w.gruB   = (__hip_bfloat16*)(ws + off);    off += 512 * 288 / 2;
    w.roB    = (__hip_bfloat16*)(ws + off);    off += 256 * 288 / 2;
    w.gruBias = ws + off;                      off += 512;
    w.roBias  = ws + off;                      off += 256;
    w.indptr  = (int*)(ws + off);              off += KN_TOT + 8;
    w.cursor  = (int*)(ws + off);              off += KN_TOT;
    w.partial = (int*)(ws + off);              off += 4096;
    w.elist   = (int*)(ws + off);              off += E_TOT;
    w.pooled  = ws + off;                      off += 64 * 128;
    w.x1      = ws + off;                      off += 64 * 256;
    w.x2      = ws + off;                      off += 64 * 128;

    // ---- merged CSR build ----
    hipMemsetAsync(w.cursor, 0, KN_TOT * sizeof(int), stream);
    hist2_kernel<<<(E_TOT + 255) / 256, 256, 0, stream>>>(bi_dst, bi_et, knn_dst, knn_et, w.cursor);
    scan1_kernel<<<KN_TOT / 256, 256, 0, stream>>>(w.cursor, w.indptr, w.partial);
    scan2b_kernel<<<1, 256, 0, stream>>>(w.partial, KN_TOT / 256, w.indptr + KN_TOT, E_TOT);
    scan3c_kernel<<<KN_TOT / 256, 256, 0, stream>>>(w.indptr, w.partial, w.cursor);
    fill2_kernel<<<(E_TOT + 255) / 256, 256, 0, stream>>>(bi_src, bi_dst, bi_et,
                                                          knn_src, knn_dst, knn_et,
                                                          w.cursor, w.elist);

    // Stage 1: bond graph (5 etypes), Fin=64
    run_stage<5>(stream, feat, nullptr, 64, s1, w, w.indptr, w.r1b);
    // Stage 2: knn graph (9 etypes), feat = stage-1 readout (bf16)
    __hip_bfloat16* r2b = (__hip_bfloat16*)w.G;   // first half of G
    run_stage<9>(stream, nullptr, w.r1b, 128, s2, w, w.indptr + KN_BI, r2b);

    // Stage 3: ligand pooling + MLP
    pool_kernel<<<64, 128, 0, stream>>>((const ushort*)r2b, w.pooled);
    {
        dim3 g1(1, 4);
        gemm_kernel<<<g1, 256, 0, stream>>>(w.pooled, 128, w0, 256, b0, w.x1, 256, 128, 1);
        dim3 g2(1, 2);
        gemm_kernel<<<g2, 256, 0, stream>>>(w.x1, 256, w1, 128, b1, w.x2, 128, 256, 1);
    }
    out_kernel<<<64, 64, 0, stream>>>(w.x2, wo, bo, (float*)d_out);
}

// Round 14
// 725.131 us; speedup vs baseline: 1.1049x; 1.0083x over previous
//
#include <hip/hip_runtime.h>
#include <hip/hip_bf16.h>

#define N_NODES 50176
#define PER 392
#define E_BI (N_NODES * 4)      // 200704
#define E_KNN (N_NODES * 16)    // 802816
#define E_TOT (E_BI + E_KNN)    // 1003520
#define KN_BI (N_NODES * 5)     // 250880
#define KN_TOT (N_NODES * 14)   // 702464
#define AH_S 416                // ah row stride (shorts): [a(128)|h(128)|cnt(32)|feat(128)]
#define AH_U 208                // ... in uints

typedef __attribute__((ext_vector_type(8))) short short8;
typedef __attribute__((ext_vector_type(4))) float float4v;
typedef unsigned int uint;
typedef unsigned short ushort;

__device__ __forceinline__ float sigmoidf_(float x) { return 1.f / (1.f + __expf(-x)); }
__device__ __forceinline__ ushort f2bu(float x) {
    __hip_bfloat16 t = __float2bfloat16(x);
    return *reinterpret_cast<ushort*>(&t);
}
__device__ __forceinline__ float blo(uint u) { return __uint_as_float(u << 16); }
__device__ __forceinline__ float bhi(uint u) { return __uint_as_float(u & 0xFFFF0000u); }

// direct global->LDS DMA, 16B per lane; LDS dest = wave-uniform base + lane*16
__device__ __forceinline__ void gld_lds16(const ushort* g, ushort* l)
{
    __builtin_amdgcn_global_load_lds(
        (const __attribute__((address_space(1))) void*)g,
        (__attribute__((address_space(3))) void*)l, 16, 0, 0);
}

// ================= fused aggregate + per-etype transform (v4 — measured optimum) ======
// Block = 32 node rows, 256 threads: 8 threads/row (16 ch each, 2x16B loads/edge).
// NOTE: r8 (thread reshape), r11 (parity split), r12 (pairwise unroll) all regressed
// vs this exact loop body — do not reshape the gather.
template<int NET>
__global__ __launch_bounds__(256) void msg_kernel(
    const uint* __restrict__ hb,           // [N][64] uints (h bf16 packed)
    const int* __restrict__ indptr,        // [N*NET+1] slice (absolute into elist)
    const int* __restrict__ elist,
    const ushort* __restrict__ Bfrag,      // fragment-ordered weights
    ushort* __restrict__ aout)             // target ah buffer; write cols 0..127
{
    __shared__ ushort As[4][32][40];       // 10.25 KB, chunk-major, 80B rows
    const int tid = threadIdx.x;
    const int bm = blockIdx.x * 32;
    const int wave = tid >> 6, lane = tid & 63;
    const int quad = lane >> 4, lrow = lane & 15;
    const int wr = wave & 1, wc = wave >> 1;
    const int r = tid >> 3;                // node row 0..31
    const int oct = tid & 7;               // 16-ch group
    const int v = bm + r;

    uint* AsU = (uint*)As;                 // [ch][r][20] uints

    float4v acc[4] = {};

    for (int et = 0; et < NET; et++) {
        const int beg = indptr[v * NET + et], end = indptr[v * NET + et + 1];
        float av[16];
#pragma unroll
        for (int i = 0; i < 16; i++) av[i] = 0.f;

        for (int j = beg; j < end; j++) {
            int src = elist[j];
            const uint4* hp = (const uint4*)(hb + (size_t)src * 64 + oct * 8);
            uint4 u0 = hp[0];
            uint4 u1 = hp[1];
            av[0] += blo(u0.x); av[1] += bhi(u0.x);
            av[2] += blo(u0.y); av[3] += bhi(u0.y);
            av[4] += blo(u0.z); av[5] += bhi(u0.z);
            av[6] += blo(u0.w); av[7] += bhi(u0.w);
            av[8]  += blo(u1.x); av[9]  += bhi(u1.x);
            av[10] += blo(u1.y); av[11] += bhi(u1.y);
            av[12] += blo(u1.z); av[13] += bhi(u1.z);
            av[14] += blo(u1.w); av[15] += bhi(u1.w);
        }

        __syncthreads();                   // previous etype's As reads complete
        {
            int base = ((oct >> 1) * 32 + r) * 20 + (oct & 1) * 8;
#pragma unroll
            for (int u = 0; u < 8; u++)
                AsU[base + u] = (uint)f2bu(av[2 * u]) | ((uint)f2bu(av[2 * u + 1]) << 16);
        }
        __syncthreads();

#pragma unroll
        for (int ch = 0; ch < 4; ch++) {
            short8 af = *(const short8*)&As[ch][wr * 16 + lrow][quad * 8];
            const ushort* bp = Bfrag + ((size_t)(((et * 4 + ch) * 2 + wc) * 4) << 9) + lane * 8;
#pragma unroll
            for (int j2 = 0; j2 < 4; j2++) {
                short8 bfr = *(const short8*)(bp + j2 * 512);
                acc[j2] = __builtin_amdgcn_mfma_f32_16x16x32_bf16(af, bfr, acc[j2], 0, 0, 0);
            }
        }
    }

#pragma unroll
    for (int j2 = 0; j2 < 4; j2++) {
        int col = wc * 64 + j2 * 16 + lrow;
#pragma unroll
        for (int rr = 0; rr < 4; rr++) {
            size_t row = (size_t)(bm + wr * 16 + quad * 4 + rr);
            aout[row * AH_S + col] = f2bu(acc[j2][rr]);
        }
    }
}

// ================= GRU GEMM with fused gate epilogue (ping-pong, race-free) ============
// Tile staging via global_load_lds width=16 (no VGPR round-trip).
__global__ __launch_bounds__(256) void gru_gemm_kernel(
    const ushort* __restrict__ A,          // ahIn base, lda AH_S
    const ushort* __restrict__ Bt,         // gruB [512][288] permuted
    const float* __restrict__ bias,        // [512] permuted
    ushort* __restrict__ ahOut, ushort* __restrict__ hbS)
{
    __shared__ ushort As[128 * 32];
    __shared__ ushort Bs[128 * 32];
    const int tid = threadIdx.x;
    const int bm = blockIdx.x * 128;
    const int bn = blockIdx.y * 128;
    const int wave = tid >> 6, lane = tid & 63;
    const int quad = lane >> 4, lrow = lane & 15;
    const int wr = wave & 1, wc = wave >> 1;

    float4v acc[4][4] = {};

    for (int k0 = 0; k0 < 288; k0 += 32) {
        __syncthreads();
#pragma unroll
        for (int p = 0; p < 2; p++) {
            int lin = p * 256 + tid;
            int r = lin >> 2;
            int kc = (lin & 3) * 8;
            int wb = (p * 256 + wave * 64) * 8;       // wave-uniform LDS base (ushorts)
            gld_lds16(A + (size_t)(bm + r) * AH_S + k0 + kc, &As[wb]);
            gld_lds16(Bt + (size_t)(bn + r) * 288 + k0 + kc, &Bs[wb]);
        }
        __syncthreads();
        short8 af[4], bfr[4];
#pragma unroll
        for (int i = 0; i < 4; i++)
            af[i] = *(const short8*)&As[(wr * 64 + i * 16 + lrow) * 32 + quad * 8];
#pragma unroll
        for (int j = 0; j < 4; j++)
            bfr[j] = *(const short8*)&Bs[(wc * 64 + j * 16 + lrow) * 32 + quad * 8];
#pragma unroll
        for (int i = 0; i < 4; i++)
#pragma unroll
            for (int j = 0; j < 4; j++)
                acc[i][j] = __builtin_amdgcn_mfma_f32_16x16x32_bf16(af[i], bfr[j], acc[i][j], 0, 0, 0);
    }

    const int ch = (bn >> 7) * 32 + wc * 16 + lrow;
    const float b0 = bias[bn + wc * 64 + lrow];
    const float b1 = bias[bn + wc * 64 + 16 + lrow];
    const float b2 = bias[bn + wc * 64 + 32 + lrow];
    const float b3 = bias[bn + wc * 64 + 48 + lrow];
#pragma unroll
    for (int i = 0; i < 4; i++) {
#pragma unroll
        for (int r = 0; r < 4; r++) {
            size_t row = (size_t)(bm + wr * 64 + i * 16 + quad * 4 + r);
            float rr = sigmoidf_(acc[i][0][r] + b0);
            float zz = sigmoidf_(acc[i][1][r] + b1);
            float nn = tanhf(acc[i][2][r] + b2 + rr * (acc[i][3][r] + b3));
            float hold = __uint_as_float(((uint)A[row * AH_S + 128 + ch]) << 16);
            float hnew = (1.f - zz) * nn + zz * hold;
            ushort hu = f2bu(hnew);
            ahOut[row * AH_S + 128 + ch] = hu;
            hbS[row * 128 + ch] = hu;
        }
    }
}

// ================= readout GEMM with fused sigmoid-mul epilogue =================
__global__ __launch_bounds__(256) void ro_gemm_kernel(
    const ushort* __restrict__ A,
    const ushort* __restrict__ Bt,         // [256][288]
    const float* __restrict__ bias,        // [256] permuted
    ushort* __restrict__ rb)               // bf16 out [N,128]
{
    __shared__ ushort As[128 * 32];
    __shared__ ushort Bs[128 * 32];
    const int tid = threadIdx.x;
    const int bm = blockIdx.x * 128;
    const int bn = blockIdx.y * 128;
    const int wave = tid >> 6, lane = tid & 63;
    const int quad = lane >> 4, lrow = lane & 15;
    const int wr = wave & 1, wc = wave >> 1;

    float4v acc[4][4] = {};

    for (int k0 = 0; k0 < 288; k0 += 32) {
        __syncthreads();
#pragma unroll
        for (int p = 0; p < 2; p++) {
            int lin = p * 256 + tid;
            int r = lin >> 2;
            int kc = (lin & 3) * 8;
            int wb = (p * 256 + wave * 64) * 8;
            gld_lds16(A + (size_t)(bm + r) * AH_S + k0 + kc, &As[wb]);
            gld_lds16(Bt + (size_t)(bn + r) * 288 + k0 + kc, &Bs[wb]);
        }
        __syncthreads();
        short8 af[4], bfr[4];
#pragma unroll
        for (int i = 0; i < 4; i++)
            af[i] = *(const short8*)&As[(wr * 64 + i * 16 + lrow) * 32 + quad * 8];
#pragma unroll
        for (int j = 0; j < 4; j++)
            bfr[j] = *(const short8*)&Bs[(wc * 64 + j * 16 + lrow) * 32 + quad * 8];
#pragma unroll
        for (int i = 0; i < 4; i++)
#pragma unroll
            for (int j = 0; j < 4; j++)
                acc[i][j] = __builtin_amdgcn_mfma_f32_16x16x32_bf16(af[i], bfr[j], acc[i][j], 0, 0, 0);
    }

    const int c0 = (bn >> 7) * 64 + wc * 32 + lrow;
    const int c1 = c0 + 16;
    const float bu0 = bias[bn + wc * 64 + lrow];
    const float bv0 = bias[bn + wc * 64 + 16 + lrow];
    const float bu1 = bias[bn + wc * 64 + 32 + lrow];
    const float bv1 = bias[bn + wc * 64 + 48 + lrow];
#pragma unroll
    for (int i = 0; i < 4; i++) {
#pragma unroll
        for (int r = 0; r < 4; r++) {
            size_t row = (size_t)(bm + wr * 64 + i * 16 + quad * 4 + r);
            float o0 = sigmoidf_(acc[i][0][r] + bu0) * (acc[i][1][r] + bv0);
            float o1 = sigmoidf_(acc[i][2][r] + bu1) * (acc[i][3][r] + bv1);
            rb[row * 128 + c0] = f2bu(o0);
            rb[row * 128 + c1] = f2bu(o1);
        }
    }
}

// ================= small fp32 GEMM (stage-3 MLP only) =================
__global__ __launch_bounds__(256) void gemm_kernel(
    const float* __restrict__ A, int lda,
    const float* __restrict__ B, int ldb,
    const float* __restrict__ bias,
    float* __restrict__ C, int ldc,
    int K, int act)
{
    __shared__ float As[32][68];
    __shared__ float Bs[32][68];
    const int tid = threadIdx.x;
    const int bm = blockIdx.x * 64;
    const int bn = blockIdx.y * 64;
    const int tm = (tid & 15) * 4;
    const int tn = (tid >> 4) * 4;
    float acc[4][4] = {};

    for (int k0 = 0; k0 < K; k0 += 32) {
#pragma unroll
        for (int p = 0; p < 2; p++) {
            int lin = p * 256 + tid;
            int ar = lin >> 3;
            int ac = (lin & 7) << 2;
            float4 av = *(const float4*)(A + (size_t)(bm + ar) * lda + (k0 + ac));
            As[ac + 0][ar] = av.x;
            As[ac + 1][ar] = av.y;
            As[ac + 2][ar] = av.z;
            As[ac + 3][ar] = av.w;
            int br = lin >> 4;
            int bc = (lin & 15) << 2;
            *(float4*)&Bs[br][bc] = *(const float4*)(B + (size_t)(k0 + br) * ldb + (bn + bc));
        }
        __syncthreads();
#pragma unroll
        for (int k = 0; k < 32; k++) {
            float4 a4 = *(const float4*)&As[k][tm];
            float4 b4 = *(const float4*)&Bs[k][tn];
            float av[4] = {a4.x, a4.y, a4.z, a4.w};
            float bv[4] = {b4.x, b4.y, b4.z, b4.w};
#pragma unroll
            for (int i = 0; i < 4; i++)
#pragma unroll
                for (int j = 0; j < 4; j++)
                    acc[i][j] += av[i] * bv[j];
        }
        __syncthreads();
    }
#pragma unroll
    for (int i = 0; i < 4; i++) {
        size_t row = (size_t)(bm + tm + i);
#pragma unroll
        for (int j = 0; j < 4; j++) {
            int col = bn + tn + j;
            float val = acc[i][j] + (bias ? bias[col] : 0.f);
            if (act == 1) val = fmaxf(val, 0.f);
            C[row * ldc + col] = val;
        }
    }
}

// ================= weight prep =================
__global__ void prep_bfrag_kernel(const float* __restrict__ W, __hip_bfloat16* __restrict__ Bf,
                                  int net)
{
    int idx = blockIdx.x * blockDim.x + threadIdx.x;   // net*16384
    int m = idx & 7;
    int lane = (idx >> 3) & 63;
    int f = idx >> 9;
    int j = f & 3; f >>= 2;
    int wc = f & 1; f >>= 1;
    int ch = f & 3;
    int et = f >> 2;
    int quad = lane >> 4, lrow = lane & 15;
    int k = ch * 32 + quad * 8 + m;
    int c = wc * 64 + j * 16 + lrow;
    Bf[idx] = __float2bfloat16(W[et * 16384 + k * 128 + c]);
}

__global__ void prep_gru_kernel(const float* __restrict__ wih, const float* __restrict__ whh,
                                const float* __restrict__ bih, const float* __restrict__ bhh,
                                const float* __restrict__ b, int net,
                                __hip_bfloat16* __restrict__ Bt, float* __restrict__ bias)
{
    int idx = blockIdx.x * blockDim.x + threadIdx.x;   // 512*288
    int p = idx / 288;
    int k = idx - p * 288;
    int g = (p >> 4) & 3;
    int c = (p >> 7) * 32 + ((p >> 6) & 1) * 16 + (p & 15);
    float val = 0.f;
    if (k < 128) {                                     // from a
        if (g == 0)      val = wih[k * 384 + c];
        else if (g == 1) val = wih[k * 384 + 128 + c];
        else if (g == 2) val = wih[k * 384 + 256 + c];
    } else if (k < 256) {                              // from h
        int kk = k - 128;
        if (g == 0)      val = whh[kk * 384 + c];
        else if (g == 1) val = whh[kk * 384 + 128 + c];
        else if (g == 3) val = whh[kk * 384 + 256 + c];
    } else {                                           // cnt cols: b @ wih
        int j = k - 256;
        if (j < net && g < 3) {
            int col = g * 128 + c;
            float s = 0.f;
            for (int kk = 0; kk < 128; kk++) s += b[j * 128 + kk] * wih[kk * 384 + col];
            val = s;
        }
    }
    Bt[idx] = __float2bfloat16(val);
    if (k == 0) {
        float bv;
        if (g == 0)      bv = bih[c] + bhh[c];
        else if (g == 1) bv = bih[128 + c] + bhh[128 + c];
        else if (g == 2) bv = bih[256 + c];
        else             bv = bhh[256 + c];
        bias[p] = bv;
    }
}

__global__ void prep_ro_kernel(const float* __restrict__ iw, const float* __restrict__ jw,
                               const float* __restrict__ ib, const float* __restrict__ jb,
                               int Fin, __hip_bfloat16* __restrict__ Bt,
                               float* __restrict__ bias)
{
    int idx = blockIdx.x * blockDim.x + threadIdx.x;   // 256*288
    int p = idx / 288;
    int k = idx - p * 288;
    int j = (p >> 4) & 3;
    int s = j & 1;
    int c = ((p >> 7) & 1) * 64 + ((p >> 6) & 1) * 32 + (j >> 1) * 16 + (p & 15);
    float val = 0.f;
    if (k < 128) {
        val = s ? jw[k * 128 + c] : iw[k * 128 + c];
    } else if (k >= 160) {
        int kf = k - 160;
        if (kf < Fin && s == 0) val = iw[(128 + kf) * 128 + c];
    }
    Bt[idx] = __float2bfloat16(val);
    if (k == 0) bias[p] = s ? jb[c] : ib[c];
}

// ================= merged CSR build =================
__global__ void hist2_kernel(const int* __restrict__ bd, const int* __restrict__ be,
                             const int* __restrict__ kd, const int* __restrict__ ke,
                             int* __restrict__ counts)
{
    int e = blockIdx.x * blockDim.x + threadIdx.x;
    if (e >= E_TOT) return;
    if (e < E_BI) atomicAdd(&counts[bd[e] * 5 + be[e]], 1);
    else { int i = e - E_BI; atomicAdd(&counts[KN_BI + kd[i] * 9 + ke[i]], 1); }
}

__global__ void scan1_kernel(const int* __restrict__ counts, int* __restrict__ local_ex,
                             int* __restrict__ partial)
{
    __shared__ int s[256];
    int t = threadIdx.x;
    int i = blockIdx.x * 256 + t;
    int v = counts[i];
    s[t] = v;
    __syncthreads();
    for (int off = 1; off < 256; off <<= 1) {
        int x = 0;
        if (t >= off) x = s[t - off];
        __syncthreads();
        if (t >= off) s[t] += x;
        __syncthreads();
    }
    local_ex[i] = s[t] - v;
    if (t == 255) partial[blockIdx.x] = s[255];
}

__global__ void scan2b_kernel(int* __restrict__ partial, int nb, int* __restrict__ last, int E)
{
    __shared__ int s[256];
    int t = threadIdx.x;
    int loc[11];
    int sum = 0;
#pragma unroll
    for (int q = 0; q < 11; q++) {
        int idx = t * 11 + q;
        int v = (idx < nb) ? partial[idx] : 0;
        loc[q] = sum; sum += v;
    }
    s[t] = sum;
    __syncthreads();
    for (int off = 1; off < 256; off <<= 1) {
        int x = 0;
        if (t >= off) x = s[t - off];
        __syncthreads();
        if (t >= off) s[t] += x;
        __syncthreads();
    }
    int excl = s[t] - sum;
#pragma unroll
    for (int q = 0; q < 11; q++) {
        int idx = t * 11 + q;
        if (idx < nb) partial[idx] = excl + loc[q];
    }
    if (t == 0) *last = E;
}

__global__ void scan3c_kernel(int* __restrict__ indptr, const int* __restrict__ partial,
                              int* __restrict__ cursor)
{
    int i = blockIdx.x * 256 + threadIdx.x;
    int v = indptr[i] + partial[blockIdx.x];
    indptr[i] = v;
    cursor[i] = v;
}

__global__ void fill2_kernel(const int* __restrict__ bs, const int* __restrict__ bd,
                             const int* __restrict__ be,
                             const int* __restrict__ ks, const int* __restrict__ kd,
                             const int* __restrict__ ke,
                             int* __restrict__ cursor, int* __restrict__ elist)
{
    int e = blockIdx.x * blockDim.x + threadIdx.x;
    if (e >= E_TOT) return;
    if (e < E_BI) {
        int pos = atomicAdd(&cursor[bd[e] * 5 + be[e]], 1);
        elist[pos] = bs[e];
    } else {
        int i = e - E_BI;
        int pos = atomicAdd(&cursor[KN_BI + kd[i] * 9 + ke[i]], 1);
        elist[pos] = ks[i];
    }
}

// ================= elementwise: pad + cnt fused (no fp32 h) =================
__global__ void pad_cnt_kernel(const float* __restrict__ fsrc, const ushort* __restrict__ bsrc,
                               const int* __restrict__ indptr, int net,
                               uint* __restrict__ ahA, uint* __restrict__ ahB,
                               uint* __restrict__ hb, int Fin)
{
    int idx = blockIdx.x * blockDim.x + threadIdx.x;   // N*32
    int v = idx >> 5;
    int j = idx & 31;
    int c = j * 4;
    float4 val = make_float4(0.f, 0.f, 0.f, 0.f);
    if (bsrc) {
        uint2 u = *(const uint2*)(bsrc + (size_t)v * Fin + c);
        val.x = blo(u.x); val.y = bhi(u.x);
        val.z = blo(u.y); val.w = bhi(u.y);
    } else if (c < Fin) {
        val = *(const float4*)(fsrc + (size_t)v * Fin + c);
    }
    uint2 pk;
    pk.x = (uint)f2bu(val.x) | ((uint)f2bu(val.y) << 16);
    pk.y = (uint)f2bu(val.z) | ((uint)f2bu(val.w) << 16);
    *(uint2*)(ahA + (size_t)v * AH_U + 64 + c / 2) = pk;    // h cols (step-0 input)
    *(uint2*)(ahA + (size_t)v * AH_U + 144 + c / 2) = pk;   // feat cols
    *(uint2*)(ahB + (size_t)v * AH_U + 144 + c / 2) = pk;
    *(uint2*)(hb + (size_t)v * 64 + c / 2) = pk;
    float cv = 0.f;
    if (j < net) cv = (float)(indptr[v * net + j + 1] - indptr[v * net + j]);
    ushort u = f2bu(cv);
    ((ushort*)ahA)[(size_t)v * AH_S + 256 + j] = u;
    ((ushort*)ahB)[(size_t)v * AH_S + 256 + j] = u;
}

// pool from bf16 readout
__global__ void pool_kernel(const ushort* __restrict__ r2, float* __restrict__ pooled)
{
    int s = blockIdx.x;
    int c = threadIdx.x;
    const ushort* base = r2 + (size_t)(2 * s) * PER * 128;
    float acc = 0.f;
    for (int i = 0; i < PER; i++)
        acc += __uint_as_float(((uint)base[(size_t)i * 128 + c]) << 16);
    pooled[s * 128 + c] = acc;
}

__global__ void out_kernel(const float* __restrict__ x2, const float* __restrict__ wo,
                           const float* __restrict__ bo, float* __restrict__ out)
{
    int row = blockIdx.x;
    int t = threadIdx.x;
    float s = x2[row * 128 + t] * wo[t] + x2[row * 128 + 64 + t] * wo[64 + t];
#pragma unroll
    for (int off = 32; off; off >>= 1) s += __shfl_down(s, off);
    if (t == 0) out[row] = s + bo[0];
}

struct GGParams {
    const float *W, *b, *wih, *whh, *bih, *bhh, *iw, *ib, *jw, *jb;
};

struct WsPtrs {
    __hip_bfloat16 *ah0, *ah1;   // [N,416] bf16 ping-pong
    float* G;                    // 2*n128 floats: r2b (bf16) | hb
    uint* hb;
    __hip_bfloat16* r1b;
    __hip_bfloat16 *bfragB, *gruB, *roB;
    float *gruBias, *roBias;
    int *indptr, *cursor, *partial, *elist;
    float *pooled, *x1, *x2;
};

template<int NET>
static void run_stage(hipStream_t st, const float* featF, const __hip_bfloat16* featB, int Fin,
                      const GGParams& p, const WsPtrs& w, const int* indptr_slice,
                      __hip_bfloat16* rout_b)
{
    const int N = N_NODES;
    ushort* ahA = (ushort*)w.ah0;
    ushort* ahB = (ushort*)w.ah1;
    ushort* hbS = (ushort*)w.hb;

    prep_bfrag_kernel<<<(NET * 16384) / 256, 256, 0, st>>>(p.W, w.bfragB, NET);
    prep_gru_kernel<<<(512 * 288) / 256, 256, 0, st>>>(p.wih, p.whh, p.bih, p.bhh, p.b, NET,
                                                       w.gruB, w.gruBias);
    prep_ro_kernel<<<(256 * 288) / 256, 256, 0, st>>>(p.iw, p.jw, p.ib, p.jb, Fin,
                                                      w.roB, w.roBias);

    pad_cnt_kernel<<<(N * 32) / 256, 256, 0, st>>>(featF, (const ushort*)featB,
                                                   indptr_slice, NET,
                                                   (uint*)ahA, (uint*)ahB, w.hb, Fin);

    ushort* ahIn = ahA;
    ushort* ahOut = ahB;
    for (int step = 0; step < 2; step++) {
        msg_kernel<NET><<<N / 32, 256, 0, st>>>(w.hb, indptr_slice, w.elist,
                                                (ushort*)w.bfragB, ahIn);
        dim3 g(N / 128, 4);
        gru_gemm_kernel<<<g, 256, 0, st>>>(ahIn, (ushort*)w.gruB, w.gruBias, ahOut, hbS);
        ushort* t = ahIn; ahIn = ahOut; ahOut = t;
    }
    dim3 gr(N / 128, 2);
    ro_gemm_kernel<<<gr, 256, 0, st>>>(ahIn + 128, (ushort*)w.roB, w.roBias,
                                       (ushort*)rout_b);
}

extern "C" void kernel_launch(void* const* d_in, const int* in_sizes, int n_in,
                              void* d_out, int out_size, void* d_ws, size_t ws_size,
                              hipStream_t stream)
{
    const float* feat    = (const float*)d_in[0];
    const int*   bi_src  = (const int*)d_in[1];
    const int*   bi_dst  = (const int*)d_in[2];
    const int*   bi_et   = (const int*)d_in[3];
    const int*   knn_src = (const int*)d_in[4];
    const int*   knn_dst = (const int*)d_in[5];
    const int*   knn_et  = (const int*)d_in[6];

    GGParams s1 { (const float*)d_in[8],  (const float*)d_in[9],  (const float*)d_in[10],
                  (const float*)d_in[11], (const float*)d_in[12], (const float*)d_in[13],
                  (const float*)d_in[14], (const float*)d_in[15], (const float*)d_in[16],
                  (const float*)d_in[17] };
    GGParams s2 { (const float*)d_in[18], (const float*)d_in[19], (const float*)d_in[20],
                  (const float*)d_in[21], (const float*)d_in[22], (const float*)d_in[23],
                  (const float*)d_in[24], (const float*)d_in[25], (const float*)d_in[26],
                  (const float*)d_in[27] };
    const float* w0 = (const float*)d_in[28];
    const float* b0 = (const float*)d_in[29];
    const float* w1 = (const float*)d_in[30];
    const float* b1 = (const float*)d_in[31];
    const float* wo = (const float*)d_in[32];
    const float* bo = (const float*)d_in[33];

    const int N = N_NODES;
    const size_t n128 = (size_t)N * 128;

    float* ws = (float*)d_ws;
    WsPtrs w;
    size_t off = 0;
    w.ah0    = (__hip_bfloat16*)(ws + off);    off += (size_t)N * 208;
    w.ah1    = (__hip_bfloat16*)(ws + off);    off += (size_t)N * 208;
    w.G      = ws + off;                       off += 2 * n128;
    w.hb     = (uint*)(w.G + n128);            // second half of G
    w.r1b    = (__hip_bfloat16*)(ws + off);    off += n128 / 2;
    w.bfragB = (__hip_bfloat16*)(ws + off);    off += 9 * 16384 / 2;
    w.gruB   = (__hip_bfloat16*)(ws + off);    off += 512 * 288 / 2;
    w.roB    = (__hip_bfloat16*)(ws + off);    off += 256 * 288 / 2;
    w.gruBias = ws + off;                      off += 512;
    w.roBias  = ws + off;                      off += 256;
    w.indptr  = (int*)(ws + off);              off += KN_TOT + 8;
    w.cursor  = (int*)(ws + off);              off += KN_TOT;
    w.partial = (int*)(ws + off);              off += 4096;
    w.elist   = (int*)(ws + off);              off += E_TOT;
    w.pooled  = ws + off;                      off += 64 * 128;
    w.x1      = ws + off;                      off += 64 * 256;
    w.x2      = ws + off;                      off += 64 * 128;

    // ---- merged CSR build ----
    hipMemsetAsync(w.cursor, 0, KN_TOT * sizeof(int), stream);
    hist2_kernel<<<(E_TOT + 255) / 256, 256, 0, stream>>>(bi_dst, bi_et, knn_dst, knn_et, w.cursor);
    scan1_kernel<<<KN_TOT / 256, 256, 0, stream>>>(w.cursor, w.indptr, w.partial);
    scan2b_kernel<<<1, 256, 0, stream>>>(w.partial, KN_TOT / 256, w.indptr + KN_TOT, E_TOT);
    scan3c_kernel<<<KN_TOT / 256, 256, 0, stream>>>(w.indptr, w.partial, w.cursor);
    fill2_kernel<<<(E_TOT + 255) / 256, 256, 0, stream>>>(bi_src, bi_dst, bi_et,
                                                          knn_src, knn_dst, knn_et,
                                                          w.cursor, w.elist);

    // Stage 1: bond graph (5 etypes), Fin=64
    run_stage<5>(stream, feat, nullptr, 64, s1, w, w.indptr, w.r1b);
    // Stage 2: knn graph (9 etypes), feat = stage-1 readout (bf16)
    __hip_bfloat16* r2b = (__hip_bfloat16*)w.G;   // first half of G
    run_stage<9>(stream, nullptr, w.r1b, 128, s2, w, w.indptr + KN_BI, r2b);

    // Stage 3: ligand pooling + MLP
    pool_kernel<<<64, 128, 0, stream>>>((const ushort*)r2b, w.pooled);
    {
        dim3 g1(1, 4);
        gemm_kernel<<<g1, 256, 0, stream>>>(w.pooled, 128, w0, 256, b0, w.x1, 256, 128, 1);
        dim3 g2(1, 2);
        gemm_kernel<<<g2, 256, 0, stream>>>(w.x1, 256, w1, 128, b1, w.x2, 128, 256, 1);
    }
    out_kernel<<<64, 64, 0, stream>>>(w.x2, wo, bo, (float*)d_out);
}